// Round 6
// baseline (723.766 us; speedup 1.0000x reference)
//
#include <hip/hip_runtime.h>

#define H 96
#define W 96
#define CIN 1024
#define NPIX 9216          // 96*96
#define NCH 54             // 18 cls + 36 reg channels
#define NA 82944           // 9216*9 anchors
#define TOPN 6000
#define NW 94              // ceil(6000/64)
#define POSN 300
#define CAND_CAP 8192
#define RQ 8               // k_rank j-range split factor
#define RCHUNK 1024        // CAND_CAP / RQ

typedef _Float16 half8_t __attribute__((ext_vector_type(8)));
typedef float f32x4 __attribute__((ext_vector_type(4)));

#define CIP 40             // padded ci stride in halves (80 B: 16B-aligned, 2-way banks = free)
#define XS_PLANE 11760     // 3*98*40 halves
#define HP_SPLIT 4718592   // 4*9216*128 floats per K-split buffer

// ---------------------------------------------------------------------------
// init: hist/ctrl <- 0
// ---------------------------------------------------------------------------
__global__ void k_init(unsigned int* __restrict__ hist, unsigned int* __restrict__ ctrl) {
    int t = blockIdx.x * 256 + threadIdx.x;
    if (t < 65536) hist[t] = 0u;
    else if (t < 65536 + 16) ctrl[t - 65536] = 0u;
}

// ---------------------------------------------------------------------------
// x transpose + fp16 split: x[ci][px] fp32 -> xt_h[px][ci], xt_l[px][ci]
// half8 (16B/lane) vectorized stores.
// ---------------------------------------------------------------------------
__global__ __launch_bounds__(256) void k_xtr(const float* __restrict__ x,
                                             _Float16* __restrict__ xh,
                                             _Float16* __restrict__ xl) {
    __shared__ float t[64 * 65];
    const int tid = threadIdx.x;
    const int px0 = blockIdx.x * 64, ci0 = blockIdx.y * 64;
    for (int i = tid; i < 4096; i += 256) {
        int ci = i >> 6, px = i & 63;
        t[ci * 65 + px] = x[(size_t)(ci0 + ci) * NPIX + px0 + px];
    }
    __syncthreads();
    for (int i = tid; i < 512; i += 256) {     // 64 px x 8 ci-octets
        int px = i >> 3, q = i & 7;
        _Float16 h8[8], l8[8];
#pragma unroll
        for (int j = 0; j < 8; ++j) {
            float v = t[(q * 8 + j) * 65 + px];
            _Float16 h = (_Float16)v;
            h8[j] = h;
            l8[j] = (_Float16)((v - (float)h) * 2048.f);
        }
        size_t o = (size_t)(px0 + px) * 1024 + ci0 + q * 8;
        *(half8_t*)(xh + o) = *(half8_t*)h8;
        *(half8_t*)(xl + o) = *(half8_t*)l8;
    }
}

// ---------------------------------------------------------------------------
// weight transform to MFMA-fragment order + fp16 split (coalesced).
// R4: g-loop split onto blockIdx.z -> 512 blocks (was 128; half the GPU idle).
// ---------------------------------------------------------------------------
__global__ __launch_bounds__(256) void k_wtr(const float* __restrict__ wr,
                                             _Float16* __restrict__ wt2) {
    __shared__ float tile[32 * 292];
    const int cb = blockIdx.x, cc = blockIdx.y, g = blockIdx.z;
    const int tid = threadIdx.x;
    for (int i = tid; i < 32 * 288; i += 256) {
        int row = i / 288, col = i - row * 288;
        tile[row * 292 + col] = wr[(size_t)(cb * 128 + g * 32 + row) * 9216 + cc * 288 + col];
    }
    __syncthreads();
#pragma unroll
    for (int k = 0; k < 9; ++k) {
        int G = k * 256 + tid;           // < 2304
        int tap = G >> 8, r = G & 255;
        int pl = r >> 7, ntl = (r >> 6) & 1, l = r & 63;
        int co_loc = ntl * 16 + (l & 15);
        int ci_b = (l >> 4) * 8;
        _Float16 o8[8];
#pragma unroll
        for (int j = 0; j < 8; ++j) {
            float v = tile[co_loc * 292 + (ci_b + j) * 9 + tap];
            _Float16 h = (_Float16)v;
            o8[j] = pl ? (_Float16)((v - (float)h) * 2048.f) : h;
        }
        _Float16* dst = wt2 + ((size_t)((tap * 4 + cb) * 32 + cc)) * 8192 +
                        (size_t)(pl * 8 + (g * 2 + ntl)) * 512 + l * 8;
        *(half8_t*)dst = *(half8_t*)o8;
    }
}

// ---------------------------------------------------------------------------
// MFMA implicit-GEMM conv3x3(1024->512), K-split by 4.
// fp16 2-plane split: h = Ah*Bh + (Ah*Bl' + Al'*Bh)/2048.
//
// R6: 8-WAVE / 512-THREAD BLOCKS (occupancy restructure). Same block work
// (1 row x 128 co, 8 ci-chunks) but wave = 3 m-tiles x 2 n-tiles:
//   acc 96->48 VGPR, B-prefetch 32->16, xr 36->20  => ~80-100 VGPR peak
// (was 128-cap-bound at 2 waves/SIMD = 21% occupancy, MfmaUtil 49%).
// __launch_bounds__(512,4) caps at 128 with margin - R2's spill disaster
// came from ADDING 32 VGPRs to a full budget; this SUBTRACTS 64.
// Grid 1536 x 512thr: exactly 3 residency rounds at 2 blocks/CU (or 2
// rounds at 3 blocks/CU if VGPR<=64; LDS 3x50.7KB fits 160KB) - no
// quantization tail either way. A-fragment LDS re-reads double (4 waves
// share an mg vs 2) - conflicts ~2x, hidden by 2x+ occupancy.
//
// Y-BAND XCD SWIZZLE: with round-robin bid%8 -> XCD dispatch, XCD k gets
// rows [12k,12k+12) for ALL (cb,ks).
// Epilogue LDS tile padded 96x132 f32 (breaks 4-way store bank conflict).
// ---------------------------------------------------------------------------
__global__ __launch_bounds__(512, 4) void k_conv(
    const _Float16* __restrict__ xth, const _Float16* __restrict__ xtl,
    const _Float16* __restrict__ wt2, float* __restrict__ hp) {
    __shared__ __align__(16) char smem[50688];   // xs 47040 B; epilogue 96x132 f32
    _Float16* xs = (_Float16*)smem;

    const int tid = threadIdx.x;
    const int bid = blockIdx.x;
    const int xcd = bid & 7;
    const int i8  = bid >> 3;          // 0..191
    const int y   = xcd * 12 + (i8 % 12);
    const int cbks = i8 / 12;          // 0..15
    const int cb  = cbks & 3;          // co block of 128
    const int ks  = cbks >> 2;         // K-split quarter (0..3)
    const int l  = tid & 63;
    const int wv = tid >> 6;          // 0..7
    const int mg = wv & 1;            // m-group (0..1): px half
    const int ng = wv >> 1;           // n-group (0..3): co quarter
    const int lm = l & 15;
    const int lk = l >> 4;            // 0..3

    f32x4 acc_h[3][2];
    f32x4 acc_x[3][2];
#pragma unroll
    for (int m2 = 0; m2 < 3; ++m2)
#pragma unroll
        for (int nt = 0; nt < 2; ++nt) {
            acc_h[m2][nt] = (f32x4){0.f, 0.f, 0.f, 0.f};
            acc_x[m2][nt] = (f32x4){0.f, 0.f, 0.f, 0.f};
        }

    // zero px pad columns (pxp = 0 and 97), both planes, 3 rows
    if (tid < 480) {
        int pl = tid / 240, j = tid - pl * 240;
        int r = j / 80, j2 = j - r * 80;
        int side = j2 / 40, c = j2 - side * 40;
        xs[pl * XS_PLANE + (r * 98 + side * 97) * CIP + c] = (_Float16)0.f;
    }

    // 2304 float4 items (2 planes x 3 rows x 96 px x 4 quads) over 512 thr
    auto ldx = [&](float4* xr, int cc_) {
#pragma unroll
        for (int k = 0; k < 5; ++k) {
            int item = k * 512 + tid;
            if (item < 2304) {
                int pl = (item >= 1152) ? 1 : 0;
                int j = item - pl * 1152;
                int r = j / 384, j2 = j - r * 384;
                int px = j2 >> 2, q = j2 & 3;
                int yy = y + r - 1;
                float4 v = {0.f, 0.f, 0.f, 0.f};
                if (yy >= 0 && yy < H)
                    v = *(const float4*)((pl ? xtl : xth) + (size_t)(yy * 96 + px) * 1024 + cc_ * 32 + q * 8);
                xr[k] = v;
            }
        }
    };
    auto stx = [&](const float4* xr) {
#pragma unroll
        for (int k = 0; k < 5; ++k) {
            int item = k * 512 + tid;
            if (item < 2304) {
                int pl = (item >= 1152) ? 1 : 0;
                int j = item - pl * 1152;
                int r = j / 384, j2 = j - r * 384;
                int px = j2 >> 2, q = j2 & 3;
                *(float4*)(xs + pl * XS_PLANE + (r * 98 + px + 1) * CIP + q * 8) = xr[k];
            }
        }
    };
    auto ldb = [&](half8_t* bh, half8_t* bl, int cc_, int tap_) {
        const _Float16* base = wt2 + ((size_t)((tap_ * 4 + cb) * 32 + cc_) * 16) * 512 + (size_t)l * 8;
#pragma unroll
        for (int nt = 0; nt < 2; ++nt) {
            bh[nt] = *(const half8_t*)(base + (size_t)(ng * 2 + nt) * 512);
            bl[nt] = *(const half8_t*)(base + (size_t)(8 + ng * 2 + nt) * 512);
        }
    };

    const int cc0 = ks * 8;
    const int ccE = cc0 + 8;
    float4 xr[5];
    ldx(xr, cc0);
    half8_t bnh[2], bnl[2];
    ldb(bnh, bnl, cc0, 0);

    for (int cc = cc0; cc < ccE; ++cc) {
        __syncthreads();           // previous chunk's xs reads complete
        stx(xr);
        __syncthreads();           // xs visible
        const int ccn = (cc + 1 < ccE) ? cc + 1 : cc;
        ldx(xr, ccn);              // prefetch next chunk's x (in flight during taps)

#pragma unroll
        for (int tap = 0; tap < 9; ++tap) {
            half8_t bh[2], bl[2];
#pragma unroll
            for (int nt = 0; nt < 2; ++nt) { bh[nt] = bnh[nt]; bl[nt] = bnl[nt]; }
            const int ntap = (tap == 8) ? 0 : tap + 1;
            const int ncc  = (tap == 8) ? ccn : cc;
            ldb(bnh, bnl, ncc, ntap);   // prefetch next tap's B

            const int ky = tap / 3, kx = tap - 3 * (tap / 3);
            half8_t ah[3], al[3];
#pragma unroll
            for (int m2 = 0; m2 < 3; ++m2) {
                const int pxp = (mg * 3 + m2) * 16 + lm + kx;
                ah[m2] = *(const half8_t*)(xs + (ky * 98 + pxp) * CIP + lk * 8);
                al[m2] = *(const half8_t*)(xs + XS_PLANE + (ky * 98 + pxp) * CIP + lk * 8);
            }
#pragma unroll
            for (int m2 = 0; m2 < 3; ++m2)
#pragma unroll
                for (int nt = 0; nt < 2; ++nt)
                    acc_h[m2][nt] = __builtin_amdgcn_mfma_f32_16x16x32_f16(ah[m2], bh[nt], acc_h[m2][nt], 0, 0, 0);
#pragma unroll
            for (int m2 = 0; m2 < 3; ++m2)
#pragma unroll
                for (int nt = 0; nt < 2; ++nt)
                    acc_x[m2][nt] = __builtin_amdgcn_mfma_f32_16x16x32_f16(ah[m2], bl[nt], acc_x[m2][nt], 0, 0, 0);
#pragma unroll
            for (int m2 = 0; m2 < 3; ++m2)
#pragma unroll
                for (int nt = 0; nt < 2; ++nt)
                    acc_x[m2][nt] = __builtin_amdgcn_mfma_f32_16x16x32_f16(al[m2], bh[nt], acc_x[m2][nt], 0, 0, 0);
        }
    }

    // ---- epilogue: combine planes, bounce through LDS, coalesced store ----
    __syncthreads();
    float* cs = (float*)smem;
#pragma unroll
    for (int m2 = 0; m2 < 3; ++m2)
#pragma unroll
        for (int nt = 0; nt < 2; ++nt) {
            int co = (ng * 2 + nt) * 16 + lm;
#pragma unroll
            for (int r = 0; r < 4; ++r) {
                int px = (mg * 3 + m2) * 16 + lk * 4 + r;
                cs[px * 132 + co] = acc_h[m2][nt][r] + acc_x[m2][nt][r] * (1.f / 2048.f);
            }
        }
    __syncthreads();
    float4* dst = (float4*)(hp + ((size_t)(ks * 4 + cb) * NPIX + y * 96) * 128);
    for (int i = tid; i < 3072; i += 512) {
        int px = i >> 5, c4 = i & 31;
        dst[i] = *(const float4*)(cs + px * 132 + c4 * 4);
    }
}

// ---------------------------------------------------------------------------
// post: h = relu(hp0+hp1+hp2+hp3+b_rpn) staged in LDS; 1x1 convs (54 ch).
// ---------------------------------------------------------------------------
__global__ __launch_bounds__(256, 2) void k_post(const float* __restrict__ hp,
                                                 const float* __restrict__ br,
                                                 const float* __restrict__ wcl,
                                                 const float* __restrict__ wrg,
                                                 const float* __restrict__ bcl,
                                                 const float* __restrict__ brg,
                                                 float* __restrict__ accum) {
    __shared__ float hsm[24 * 520];
    __shared__ float wcs[54 * 130];
    const int tid = threadIdx.x;
    const int gp0 = blockIdx.x * 24;

    for (int i = tid; i < 24 * 512; i += 256) {
        int px = i >> 9, ci = i & 511;
        int cbk = ci >> 7, co = ci & 127;
        size_t off = ((size_t)cbk * NPIX + gp0 + px) * 128 + co;
        float v = hp[off] + hp[off + HP_SPLIT] + hp[off + 2 * (size_t)HP_SPLIT] +
                  hp[off + 3 * (size_t)HP_SPLIT] + br[ci];
        hsm[px * 520 + ci] = fmaxf(v, 0.f);
    }

    const int px  = tid >> 3;
    const int chb = tid & 7;
    float part[7];
#pragma unroll
    for (int k = 0; k < 7; ++k) part[k] = 0.f;

    for (int chunk = 0; chunk < 4; ++chunk) {
        __syncthreads();
        for (int i = tid; i < 54 * 128; i += 256) {
            int ch = i >> 7, j = i & 127;
            wcs[ch * 130 + j] = (ch < 18) ? wcl[ch * 512 + chunk * 128 + j]
                                          : wrg[(ch - 18) * 512 + chunk * 128 + j];
        }
        __syncthreads();
        if (px < 24) {
            const float4* hv = (const float4*)(hsm + px * 520 + chunk * 128);
#pragma unroll 4
            for (int q = 0; q < 32; ++q) {
                float4 hq = hv[q];
#pragma unroll
                for (int k = 0; k < 7; ++k) {
                    int ch = chb * 7 + k;
                    if (ch < 54) {
                        float4 wq = *(const float4*)(wcs + ch * 130 + q * 4);
                        part[k] += hq.x * wq.x + hq.y * wq.y + hq.z * wq.z + hq.w * wq.w;
                    }
                }
            }
        }
    }
    if (px < 24) {
#pragma unroll
        for (int k = 0; k < 7; ++k) {
            int ch = chb * 7 + k;
            if (ch < 54) {
                float b = (ch < 18) ? bcl[ch] : brg[ch - 18];
                accum[(size_t)(gp0 + px) * NCH + ch] = part[k] + b;
            }
        }
    }
}

// ---------------------------------------------------------------------------
// decode: anchors + reg -> proposals/clipped boxes; cls -> d = c1-c0; histogram
// ---------------------------------------------------------------------------
__device__ __forceinline__ unsigned int key_of(float d) {
    unsigned int u = __float_as_uint(d);
    unsigned int k = (u & 0x80000000u) ? ~u : (u | 0x80000000u);  // asc in d
    return ~k;                                                     // asc key = desc d
}

__global__ void k_decode(const float* __restrict__ accum, const float* __restrict__ anchors,
                         float* __restrict__ props, float* __restrict__ boxes,
                         float* __restrict__ cls2, float* __restrict__ dval,
                         unsigned int* __restrict__ hist) {
    int idx = blockIdx.x * 256 + threadIdx.x;
    if (idx >= NA) return;
    int p = idx / 9, a = idx - p * 9;
    const float* ac = accum + p * NCH;
    float c0 = ac[2 * a], c1 = ac[2 * a + 1];
    float r0 = ac[18 + 4 * a + 0], r1 = ac[18 + 4 * a + 1];
    float r2 = ac[18 + 4 * a + 2], r3 = ac[18 + 4 * a + 3];
    const float* A = anchors + (size_t)idx * 4;
    float aw = A[2] - A[0] + 1.f, ah = A[3] - A[1] + 1.f;
    float ax = A[0] + 0.5f * (aw - 1.f), ay = A[1] + 0.5f * (ah - 1.f);
    float px = ax + aw * r0, py = ay + ah * r1;
    float pw = aw * expf(r2), ph = ah * expf(r3);
    float p0 = px - 0.5f * (pw - 1.f), p1 = py - 0.5f * (ph - 1.f);
    float p2 = px + 0.5f * (pw - 1.f), p3 = py + 0.5f * (ph - 1.f);
    props[idx * 4 + 0] = p0; props[idx * 4 + 1] = p1;
    props[idx * 4 + 2] = p2; props[idx * 4 + 3] = p3;
    boxes[idx * 4 + 0] = fminf(fmaxf(p0, 0.f), (float)(1536 - 1));
    boxes[idx * 4 + 1] = fminf(fmaxf(p1, 0.f), (float)(1536 - 1));
    boxes[idx * 4 + 2] = fminf(fmaxf(p2, 0.f), (float)(1536 - 1));
    boxes[idx * 4 + 3] = fminf(fmaxf(p3, 0.f), (float)(1536 - 1));
    cls2[idx * 2 + 0] = c0; cls2[idx * 2 + 1] = c1;
    float d = c1 - c0;
    dval[idx] = d;
    atomicAdd(&hist[key_of(d) >> 16], 1u);
}

// ---------------------------------------------------------------------------
// threshold: find histogram bin T containing rank-6000.
// R4: wave-reduce before LDS atomic (old: 64-way same-address LDS-atomic
// serialization, ~25us on one CU). shfl tree + 1 atomic per wave-iteration.
// ---------------------------------------------------------------------------
__global__ __launch_bounds__(1024) void k_thresh(const unsigned int* __restrict__ hist,
                                                 unsigned int* __restrict__ ctrl) {
    __shared__ unsigned int s[256];
    __shared__ unsigned int ss[256];
    __shared__ unsigned int chunkIdx, baseCount;
    const int tid = threadIdx.x;
    if (tid < 256) s[tid] = 0u;
    __syncthreads();
    for (int i = tid; i < 65536; i += 1024) {
        unsigned int v = hist[i];
#pragma unroll
        for (int d = 32; d > 0; d >>= 1) v += __shfl_down(v, d);
        if ((tid & 63) == 0) atomicAdd(&s[i >> 8], v);
    }
    __syncthreads();
    if (tid == 0) {
        unsigned int cum = 0; int c = 0;
        for (; c < 256; ++c) { if (cum + s[c] >= TOPN) break; cum += s[c]; }
        chunkIdx = (unsigned int)c; baseCount = cum;
    }
    __syncthreads();
    if (tid < 256) ss[tid] = hist[chunkIdx * 256 + tid];
    __syncthreads();
    if (tid == 0) {
        unsigned int cum = baseCount; int b = 0;
        for (; b < 256; ++b) { cum += ss[b]; if (cum >= TOPN) break; }
        ctrl[1] = chunkIdx * 256 + (unsigned int)b;  // T
        ctrl[2] = cum;
    }
}

// ---------------------------------------------------------------------------
// compact candidates (bin <= T): per-block LDS aggregation, 1 global atomic.
// ---------------------------------------------------------------------------
__global__ __launch_bounds__(256) void k_compact(const float* __restrict__ dval,
                                                 unsigned int* __restrict__ ctrl,
                                                 unsigned long long* __restrict__ cand) {
    __shared__ unsigned int cnt, base;
    const int tid = threadIdx.x;
    const int idx = blockIdx.x * 256 + tid;
    if (tid == 0) cnt = 0u;
    __syncthreads();
    unsigned int k2 = 0; bool pass = false; unsigned int pos = 0;
    if (idx < NA) {
        k2 = key_of(dval[idx]);
        pass = (k2 >> 16) <= ctrl[1];
        if (pass) pos = atomicAdd(&cnt, 1u);
    }
    __syncthreads();
    if (tid == 0) base = atomicAdd(&ctrl[0], cnt);
    __syncthreads();
    if (pass) {
        unsigned int p = base + pos;
        if (p < CAND_CAP) cand[p] = ((unsigned long long)k2 << 32) | (unsigned int)idx;
    }
}

// ---------------------------------------------------------------------------
// rank-by-count, j-range split 8 ways: block (ci,jq) ranks candidates
// ci*256..+256 against key slice jq*1024..+1024, WRITES partial rank to
// rankp[jq*CAND_CAP + i] (no atomics, no init).
// ---------------------------------------------------------------------------
__global__ __launch_bounds__(256) void k_rankp(const unsigned long long* __restrict__ cand,
                                               const unsigned int* __restrict__ ctrl,
                                               unsigned int* __restrict__ rankp) {
    __shared__ unsigned long long sc[RCHUNK];   // 8 KB
    const int tid = threadIdx.x;
    const int ci = blockIdx.x >> 3;            // candidate chunk 0..31
    const int jq = blockIdx.x & 7;             // j-slice 0..7
    unsigned int n = ctrl[0]; if (n > CAND_CAP) n = CAND_CAP;
    const int jb = jq * RCHUNK;
    for (int i = tid; i < RCHUNK; i += 256) {
        int j = jb + i;
        sc[i] = (j < (int)n) ? cand[j] : 0xFFFFFFFFFFFFFFFFull;  // pads never < mine
    }
    __syncthreads();
    const int i = ci * 256 + tid;
    // keep ALL lanes active through the shfl loop (inactive lanes would
    // poison __shfl reads for their wave-mates)
    const unsigned long long mine = (i < (int)n) ? cand[i] : 0xFFFFFFFFFFFFFFFFull;
    const int l = tid & 63;
    int nq = (int)n - jb; if (nq < 0) nq = 0; if (nq > RCHUNK) nq = RCHUNK;
    const int nr = (nq + 63) & ~63;
    int rank = 0;
    for (int j0 = 0; j0 < nr; j0 += 64) {
        unsigned long long kj = sc[j0 + l];
#pragma unroll
        for (int b = 0; b < 64; ++b) {
            unsigned long long kb = __shfl(kj, b);
            rank += (kb < mine) ? 1 : 0;
        }
    }
    if (i < (int)n) rankp[jq * CAND_CAP + i] = (unsigned int)rank;
}

// ---------------------------------------------------------------------------
// sum the 8 partial ranks, scatter boxes/probs at final rank.
// ---------------------------------------------------------------------------
__global__ __launch_bounds__(256) void k_ranks(const unsigned long long* __restrict__ cand,
                                               const unsigned int* __restrict__ ctrl,
                                               const unsigned int* __restrict__ rankp,
                                               const float* __restrict__ boxes,
                                               const float* __restrict__ dval,
                                               float* __restrict__ topBoxes,
                                               float* __restrict__ topProbs) {
    const int i = blockIdx.x * 256 + threadIdx.x;
    unsigned int n = ctrl[0]; if (n > CAND_CAP) n = CAND_CAP;
    if (i >= (int)n) return;
    unsigned int rank = 0;
#pragma unroll
    for (int q = 0; q < RQ; ++q) rank += rankp[q * CAND_CAP + i];
    if (rank < TOPN) {
        unsigned long long mine = cand[i];
        unsigned int idx = (unsigned int)mine;
        ((float4*)topBoxes)[rank] = ((const float4*)boxes)[idx];
        topProbs[rank] = 1.f / (1.f + expf(-dval[idx]));
    }
}

// ---------------------------------------------------------------------------
// NMS suppression bitmask, triangular grid.
// R4: c-block's 64 boxes staged in LDS once per block (was 64 VMEM loads
// per lane); whole-block early-out for fully-dead triangular blocks.
// ---------------------------------------------------------------------------
__global__ __launch_bounds__(256) void k_mask(const float* __restrict__ topBoxes,
                                              unsigned long long* __restrict__ mask) {
    const int c = blockIdx.y;
    if (c < blockIdx.x * 4) return;            // whole block below diagonal
    __shared__ float4 bsh[64];
    const int tid = threadIdx.x;
    const int i = blockIdx.x * 256 + tid;
    if (tid < 64) {
        int j = c * 64 + tid;
        float4 bv = {0.f, 0.f, 0.f, 0.f};
        if (j < TOPN) bv = ((const float4*)topBoxes)[j];
        bsh[tid] = bv;
    }
    __syncthreads();
    if (i >= TOPN || c < (i >> 6)) return;
    float4 bi = ((const float4*)topBoxes)[i];
    float ai = (bi.z - bi.x + 1.f) * (bi.w - bi.y + 1.f);
    unsigned long long m = 0;
    int j0 = c * 64;
    for (int b = 0; b < 64; ++b) {
        int j = j0 + b;
        if (j >= TOPN || j <= i) continue;
        float4 bj = bsh[b];
        float aj = (bj.z - bj.x + 1.f) * (bj.w - bj.y + 1.f);
        float iw = fmaxf(fminf(bi.z, bj.z) - fmaxf(bi.x, bj.x) + 1.f, 0.f);
        float ih = fmaxf(fminf(bi.w, bj.w) - fmaxf(bi.y, bj.y) + 1.f, 0.f);
        float inter = iw * ih;
        float iou = inter / (ai + aj - inter);
        if (iou > 0.7f) m |= (1ull << b);
    }
    mask[(size_t)i * NW + c] = m;
}

// ---------------------------------------------------------------------------
// greedy scan, single wave, batched unconditional loads, early exit at 300.
// [R3-proven version. The R4 256-thread restructure coincided with a device
// abort; reverted pending isolation.]
// ---------------------------------------------------------------------------
__global__ __launch_bounds__(64) void k_scan(const unsigned long long* __restrict__ mask,
                                             const float* __restrict__ topBoxes,
                                             const float* __restrict__ topProbs,
                                             float* __restrict__ out2, float* __restrict__ out3) {
    __shared__ unsigned long long kw[NW];
    int l = threadIdx.x;
    for (int i = l; i < NW; i += 64)
        kw[i] = (i == NW - 1) ? 0x0000FFFFFFFFFFFFull : ~0ull;  // 6000 = 93*64+48
    __syncthreads();
    int kept = 0;
    for (int c = 0; c < NW && kept < POSN; ++c) {
        unsigned long long w = kw[c];
        unsigned long long m = mask[(size_t)(c * 64 + l) * NW + c];
        for (int b = 0; b < 64; ++b) {
            if ((w >> b) & 1ull) {
                unsigned long long mb = __shfl(m, b);
                w &= ~mb;
            }
        }
        if ((w >> l) & 1ull) {
            int r = kept + __popcll(w & ((1ull << l) - 1ull));
            if (r < POSN) {
                int j = c * 64 + l;
                out2[r * 4 + 0] = topBoxes[j * 4 + 0];
                out2[r * 4 + 1] = topBoxes[j * 4 + 1];
                out2[r * 4 + 2] = topBoxes[j * 4 + 2];
                out2[r * 4 + 3] = topBoxes[j * 4 + 3];
                out3[r] = topProbs[j];
            }
        }
        kept += __popcll(w);
        if (kept >= POSN) break;
        for (int c2 = c + 1 + l; c2 < NW; c2 += 64) {
            unsigned long long sup = 0;
#pragma unroll
            for (int b0 = 0; b0 < 64; b0 += 16) {
                unsigned long long t[16];
#pragma unroll
                for (int j = 0; j < 16; ++j)
                    t[j] = mask[(size_t)(c * 64 + b0 + j) * NW + c2];
#pragma unroll
                for (int j = 0; j < 16; ++j)
                    sup |= ((w >> (b0 + j)) & 1ull) ? t[j] : 0ull;
            }
            kw[c2] &= ~sup;
        }
        __syncthreads();
    }
    for (int r = kept + l; r < POSN; r += 64) {
        out2[r * 4 + 0] = 0.f; out2[r * 4 + 1] = 0.f;
        out2[r * 4 + 2] = 0.f; out2[r * 4 + 3] = 0.f;
        out3[r] = 0.f;
    }
}

// ---------------------------------------------------------------------------
// gather proposals/cls at valid_idx
// ---------------------------------------------------------------------------
__global__ void k_gather(const int* __restrict__ vidx, const float* __restrict__ props,
                         const float* __restrict__ cls2, float* __restrict__ out0,
                         float* __restrict__ out1, int nv) {
    int i = blockIdx.x * 256 + threadIdx.x;
    if (i >= nv) return;
    int v = vidx[i];
    ((float4*)out0)[i] = ((const float4*)props)[v];
    ((float2*)out1)[i] = ((const float2*)cls2)[v];
}

// ---------------------------------------------------------------------------
extern "C" void kernel_launch(void* const* d_in, const int* in_sizes, int n_in,
                              void* d_out, int out_size, void* d_ws, size_t ws_size,
                              hipStream_t stream) {
    const float* x       = (const float*)d_in[0];
    const float* w_rpn   = (const float*)d_in[1];
    const float* b_rpn   = (const float*)d_in[2];
    const float* w_cls   = (const float*)d_in[3];
    const float* b_cls   = (const float*)d_in[4];
    const float* w_reg   = (const float*)d_in[5];
    const float* b_reg   = (const float*)d_in[6];
    const float* anchors = (const float*)d_in[7];
    const int*   vidx    = (const int*)d_in[8];
    const int nv = in_sizes[8];

    char* ws = (char*)d_ws;
    float* accum            = (float*)(ws + 0);
    float* props            = (float*)(ws + 1990656);
    float* boxes            = (float*)(ws + 3317760);
    float* cls2             = (float*)(ws + 4644864);
    float* dval             = (float*)(ws + 5308416);
    unsigned int* hist      = (unsigned int*)(ws + 5640192);
    unsigned int* ctrl      = (unsigned int*)(ws + 5902336);
    unsigned long long* cand = (unsigned long long*)(ws + 5902400);
    float* topBoxes         = (float*)(ws + 5967936);
    float* topProbs         = (float*)(ws + 6063936);
    unsigned long long* mask = (unsigned long long*)(ws + 6087936);  // 4.512 MB
    _Float16* xt_h          = (_Float16*)(ws + 10599936);  // 18.87 MB
    _Float16* xt_l          = (_Float16*)(ws + 29474304);  // 18.87 MB
    _Float16* wt2           = (_Float16*)(ws + 48348672);  // 18.87 MB fragment-ordered
    float* hp               = (float*)(ws + 67223040);     // 75.5 MB (4 K-splits; ends ~143 MB)
    // partial ranks (8 x 8192 u32 = 256 KB) aliased onto xt_h's region:
    // xt_h is dead after k_conv, and k_rankp runs strictly after it.
    unsigned int* rankp     = (unsigned int*)(ws + 10599936);

    float* out0 = (float*)d_out;
    float* out1 = out0 + (size_t)nv * 4;
    float* out2 = out1 + (size_t)nv * 2;
    float* out3 = out2 + (size_t)POSN * 4;

    k_init<<<(65536 + 16 + 255) / 256, 256, 0, stream>>>(hist, ctrl);
    k_xtr<<<dim3(144, 16), 256, 0, stream>>>(x, xt_h, xt_l);
    k_wtr<<<dim3(4, 32, 4), 256, 0, stream>>>(w_rpn, wt2);
    k_conv<<<1536, 512, 0, stream>>>(xt_h, xt_l, wt2, hp);
    k_post<<<384, 256, 0, stream>>>(hp, b_rpn, w_cls, w_reg, b_cls, b_reg, accum);
    k_decode<<<(NA + 255) / 256, 256, 0, stream>>>(accum, anchors, props, boxes, cls2, dval, hist);
    k_thresh<<<1, 1024, 0, stream>>>(hist, ctrl);
    k_compact<<<(NA + 255) / 256, 256, 0, stream>>>(dval, ctrl, cand);
    k_rankp<<<32 * RQ, 256, 0, stream>>>(cand, ctrl, rankp);
    k_ranks<<<32, 256, 0, stream>>>(cand, ctrl, rankp, boxes, dval, topBoxes, topProbs);
    k_mask<<<dim3(24, NW), 256, 0, stream>>>(topBoxes, mask);
    k_scan<<<1, 64, 0, stream>>>(mask, topBoxes, topProbs, out2, out3);
    k_gather<<<(nv + 255) / 256, 256, 0, stream>>>(vidx, props, cls2, out0, out1, nv);
}

// Round 7
// 695.624 us; speedup vs baseline: 1.0405x; 1.0405x over previous
//
#include <hip/hip_runtime.h>

#define H 96
#define W 96
#define CIN 1024
#define NPIX 9216          // 96*96
#define NCH 54             // 18 cls + 36 reg channels
#define NA 82944           // 9216*9 anchors
#define TOPN 6000
#define NW 94              // ceil(6000/64)
#define POSN 300
#define CAND_CAP 8192
#define RQ 8               // k_rank j-range split factor
#define RCHUNK 1024        // CAND_CAP / RQ

typedef _Float16 half8_t __attribute__((ext_vector_type(8)));
typedef float f32x4 __attribute__((ext_vector_type(4)));

#define CIP 40             // padded ci stride in halves (80 B: 16B-aligned, 2-way banks = free)
#define XS_PLANE 11760     // 3*98*40 halves
#define HP_SPLIT 4718592   // 4*9216*128 floats per K-split buffer

// ---------------------------------------------------------------------------
// init: hist/ctrl <- 0
// ---------------------------------------------------------------------------
__global__ void k_init(unsigned int* __restrict__ hist, unsigned int* __restrict__ ctrl) {
    int t = blockIdx.x * 256 + threadIdx.x;
    if (t < 65536) hist[t] = 0u;
    else if (t < 65536 + 16) ctrl[t - 65536] = 0u;
}

// ---------------------------------------------------------------------------
// x transpose + fp16 split: x[ci][px] fp32 -> xt_h[px][ci], xt_l[px][ci]
// half8 (16B/lane) vectorized stores.
// ---------------------------------------------------------------------------
__global__ __launch_bounds__(256) void k_xtr(const float* __restrict__ x,
                                             _Float16* __restrict__ xh,
                                             _Float16* __restrict__ xl) {
    __shared__ float t[64 * 65];
    const int tid = threadIdx.x;
    const int px0 = blockIdx.x * 64, ci0 = blockIdx.y * 64;
    for (int i = tid; i < 4096; i += 256) {
        int ci = i >> 6, px = i & 63;
        t[ci * 65 + px] = x[(size_t)(ci0 + ci) * NPIX + px0 + px];
    }
    __syncthreads();
    for (int i = tid; i < 512; i += 256) {     // 64 px x 8 ci-octets
        int px = i >> 3, q = i & 7;
        _Float16 h8[8], l8[8];
#pragma unroll
        for (int j = 0; j < 8; ++j) {
            float v = t[(q * 8 + j) * 65 + px];
            _Float16 h = (_Float16)v;
            h8[j] = h;
            l8[j] = (_Float16)((v - (float)h) * 2048.f);
        }
        size_t o = (size_t)(px0 + px) * 1024 + ci0 + q * 8;
        *(half8_t*)(xh + o) = *(half8_t*)h8;
        *(half8_t*)(xl + o) = *(half8_t*)l8;
    }
}

// ---------------------------------------------------------------------------
// weight transform to MFMA-fragment order + fp16 split (coalesced).
// R4: g-loop split onto blockIdx.z -> 512 blocks (was 128; half the GPU idle).
// ---------------------------------------------------------------------------
__global__ __launch_bounds__(256) void k_wtr(const float* __restrict__ wr,
                                             _Float16* __restrict__ wt2) {
    __shared__ float tile[32 * 292];
    const int cb = blockIdx.x, cc = blockIdx.y, g = blockIdx.z;
    const int tid = threadIdx.x;
    for (int i = tid; i < 32 * 288; i += 256) {
        int row = i / 288, col = i - row * 288;
        tile[row * 292 + col] = wr[(size_t)(cb * 128 + g * 32 + row) * 9216 + cc * 288 + col];
    }
    __syncthreads();
#pragma unroll
    for (int k = 0; k < 9; ++k) {
        int G = k * 256 + tid;           // < 2304
        int tap = G >> 8, r = G & 255;
        int pl = r >> 7, ntl = (r >> 6) & 1, l = r & 63;
        int co_loc = ntl * 16 + (l & 15);
        int ci_b = (l >> 4) * 8;
        _Float16 o8[8];
#pragma unroll
        for (int j = 0; j < 8; ++j) {
            float v = tile[co_loc * 292 + (ci_b + j) * 9 + tap];
            _Float16 h = (_Float16)v;
            o8[j] = pl ? (_Float16)((v - (float)h) * 2048.f) : h;
        }
        _Float16* dst = wt2 + ((size_t)((tap * 4 + cb) * 32 + cc)) * 8192 +
                        (size_t)(pl * 8 + (g * 2 + ntl)) * 512 + l * 8;
        *(half8_t*)dst = *(half8_t*)o8;
    }
}

// ---------------------------------------------------------------------------
// MFMA implicit-GEMM conv3x3(1024->512), K-split by 4.
// fp16 2-plane split: h = Ah*Bh + (Ah*Bl' + Al'*Bh)/2048.
//
// R6/R7: 8-WAVE / 512-THREAD BLOCKS. Wave = 3 m-tiles x 2 n-tiles:
// acc 48 + B 16 + xr 20 + addressing ~= 105 VGPR.
// R7 FIX: __launch_bounds__ 2nd arg is empirically MIN BLOCKS PER CU
// (CUDA semantics) on hipcc, NOT waves/EU: R6's (512,4) forced 4 blk/CU
// = 32 waves/CU = 8 waves/SIMD => VGPR cap 64 => massive scratch spill
// (FETCH 119->534 MB, WRITE 74->200 MB, MfmaUtil 33%). (512,2) => cap
// 128, kernel fits ~105, no spill, 2 blocks/CU = 16 waves/CU (2x R5's
// latency hiding). Grid 1536 = 3 exact residency rounds.
//
// Y-BAND XCD SWIZZLE: with round-robin bid%8 -> XCD dispatch, XCD k gets
// rows [12k,12k+12) for ALL (cb,ks).
// Epilogue LDS tile padded 96x132 f32 (breaks 4-way store bank conflict).
// ---------------------------------------------------------------------------
__global__ __launch_bounds__(512, 2) void k_conv(
    const _Float16* __restrict__ xth, const _Float16* __restrict__ xtl,
    const _Float16* __restrict__ wt2, float* __restrict__ hp) {
    __shared__ __align__(16) char smem[50688];   // xs 47040 B; epilogue 96x132 f32
    _Float16* xs = (_Float16*)smem;

    const int tid = threadIdx.x;
    const int bid = blockIdx.x;
    const int xcd = bid & 7;
    const int i8  = bid >> 3;          // 0..191
    const int y   = xcd * 12 + (i8 % 12);
    const int cbks = i8 / 12;          // 0..15
    const int cb  = cbks & 3;          // co block of 128
    const int ks  = cbks >> 2;         // K-split quarter (0..3)
    const int l  = tid & 63;
    const int wv = tid >> 6;          // 0..7
    const int mg = wv & 1;            // m-group (0..1): px half
    const int ng = wv >> 1;           // n-group (0..3): co quarter
    const int lm = l & 15;
    const int lk = l >> 4;            // 0..3

    f32x4 acc_h[3][2];
    f32x4 acc_x[3][2];
#pragma unroll
    for (int m2 = 0; m2 < 3; ++m2)
#pragma unroll
        for (int nt = 0; nt < 2; ++nt) {
            acc_h[m2][nt] = (f32x4){0.f, 0.f, 0.f, 0.f};
            acc_x[m2][nt] = (f32x4){0.f, 0.f, 0.f, 0.f};
        }

    // zero px pad columns (pxp = 0 and 97), both planes, 3 rows
    if (tid < 480) {
        int pl = tid / 240, j = tid - pl * 240;
        int r = j / 80, j2 = j - r * 80;
        int side = j2 / 40, c = j2 - side * 40;
        xs[pl * XS_PLANE + (r * 98 + side * 97) * CIP + c] = (_Float16)0.f;
    }

    // 2304 float4 items (2 planes x 3 rows x 96 px x 4 quads) over 512 thr
    auto ldx = [&](float4* xr, int cc_) {
#pragma unroll
        for (int k = 0; k < 5; ++k) {
            int item = k * 512 + tid;
            if (item < 2304) {
                int pl = (item >= 1152) ? 1 : 0;
                int j = item - pl * 1152;
                int r = j / 384, j2 = j - r * 384;
                int px = j2 >> 2, q = j2 & 3;
                int yy = y + r - 1;
                float4 v = {0.f, 0.f, 0.f, 0.f};
                if (yy >= 0 && yy < H)
                    v = *(const float4*)((pl ? xtl : xth) + (size_t)(yy * 96 + px) * 1024 + cc_ * 32 + q * 8);
                xr[k] = v;
            }
        }
    };
    auto stx = [&](const float4* xr) {
#pragma unroll
        for (int k = 0; k < 5; ++k) {
            int item = k * 512 + tid;
            if (item < 2304) {
                int pl = (item >= 1152) ? 1 : 0;
                int j = item - pl * 1152;
                int r = j / 384, j2 = j - r * 384;
                int px = j2 >> 2, q = j2 & 3;
                *(float4*)(xs + pl * XS_PLANE + (r * 98 + px + 1) * CIP + q * 8) = xr[k];
            }
        }
    };
    auto ldb = [&](half8_t* bh, half8_t* bl, int cc_, int tap_) {
        const _Float16* base = wt2 + ((size_t)((tap_ * 4 + cb) * 32 + cc_) * 16) * 512 + (size_t)l * 8;
#pragma unroll
        for (int nt = 0; nt < 2; ++nt) {
            bh[nt] = *(const half8_t*)(base + (size_t)(ng * 2 + nt) * 512);
            bl[nt] = *(const half8_t*)(base + (size_t)(8 + ng * 2 + nt) * 512);
        }
    };

    const int cc0 = ks * 8;
    const int ccE = cc0 + 8;
    float4 xr[5];
    ldx(xr, cc0);
    half8_t bnh[2], bnl[2];
    ldb(bnh, bnl, cc0, 0);

    for (int cc = cc0; cc < ccE; ++cc) {
        __syncthreads();           // previous chunk's xs reads complete
        stx(xr);
        __syncthreads();           // xs visible
        const int ccn = (cc + 1 < ccE) ? cc + 1 : cc;
        ldx(xr, ccn);              // prefetch next chunk's x (in flight during taps)

#pragma unroll
        for (int tap = 0; tap < 9; ++tap) {
            half8_t bh[2], bl[2];
#pragma unroll
            for (int nt = 0; nt < 2; ++nt) { bh[nt] = bnh[nt]; bl[nt] = bnl[nt]; }
            const int ntap = (tap == 8) ? 0 : tap + 1;
            const int ncc  = (tap == 8) ? ccn : cc;
            ldb(bnh, bnl, ncc, ntap);   // prefetch next tap's B

            const int ky = tap / 3, kx = tap - 3 * (tap / 3);
            half8_t ah[3], al[3];
#pragma unroll
            for (int m2 = 0; m2 < 3; ++m2) {
                const int pxp = (mg * 3 + m2) * 16 + lm + kx;
                ah[m2] = *(const half8_t*)(xs + (ky * 98 + pxp) * CIP + lk * 8);
                al[m2] = *(const half8_t*)(xs + XS_PLANE + (ky * 98 + pxp) * CIP + lk * 8);
            }
#pragma unroll
            for (int m2 = 0; m2 < 3; ++m2)
#pragma unroll
                for (int nt = 0; nt < 2; ++nt)
                    acc_h[m2][nt] = __builtin_amdgcn_mfma_f32_16x16x32_f16(ah[m2], bh[nt], acc_h[m2][nt], 0, 0, 0);
#pragma unroll
            for (int m2 = 0; m2 < 3; ++m2)
#pragma unroll
                for (int nt = 0; nt < 2; ++nt)
                    acc_x[m2][nt] = __builtin_amdgcn_mfma_f32_16x16x32_f16(ah[m2], bl[nt], acc_x[m2][nt], 0, 0, 0);
#pragma unroll
            for (int m2 = 0; m2 < 3; ++m2)
#pragma unroll
                for (int nt = 0; nt < 2; ++nt)
                    acc_x[m2][nt] = __builtin_amdgcn_mfma_f32_16x16x32_f16(al[m2], bh[nt], acc_x[m2][nt], 0, 0, 0);
        }
    }

    // ---- epilogue: combine planes, bounce through LDS, coalesced store ----
    __syncthreads();
    float* cs = (float*)smem;
#pragma unroll
    for (int m2 = 0; m2 < 3; ++m2)
#pragma unroll
        for (int nt = 0; nt < 2; ++nt) {
            int co = (ng * 2 + nt) * 16 + lm;
#pragma unroll
            for (int r = 0; r < 4; ++r) {
                int px = (mg * 3 + m2) * 16 + lk * 4 + r;
                cs[px * 132 + co] = acc_h[m2][nt][r] + acc_x[m2][nt][r] * (1.f / 2048.f);
            }
        }
    __syncthreads();
    float4* dst = (float4*)(hp + ((size_t)(ks * 4 + cb) * NPIX + y * 96) * 128);
    for (int i = tid; i < 3072; i += 512) {
        int px = i >> 5, c4 = i & 31;
        dst[i] = *(const float4*)(cs + px * 132 + c4 * 4);
    }
}

// ---------------------------------------------------------------------------
// post: h = relu(hp0+hp1+hp2+hp3+b_rpn) staged in LDS; 1x1 convs (54 ch).
// ---------------------------------------------------------------------------
__global__ __launch_bounds__(256, 2) void k_post(const float* __restrict__ hp,
                                                 const float* __restrict__ br,
                                                 const float* __restrict__ wcl,
                                                 const float* __restrict__ wrg,
                                                 const float* __restrict__ bcl,
                                                 const float* __restrict__ brg,
                                                 float* __restrict__ accum) {
    __shared__ float hsm[24 * 520];
    __shared__ float wcs[54 * 130];
    const int tid = threadIdx.x;
    const int gp0 = blockIdx.x * 24;

    for (int i = tid; i < 24 * 512; i += 256) {
        int px = i >> 9, ci = i & 511;
        int cbk = ci >> 7, co = ci & 127;
        size_t off = ((size_t)cbk * NPIX + gp0 + px) * 128 + co;
        float v = hp[off] + hp[off + HP_SPLIT] + hp[off + 2 * (size_t)HP_SPLIT] +
                  hp[off + 3 * (size_t)HP_SPLIT] + br[ci];
        hsm[px * 520 + ci] = fmaxf(v, 0.f);
    }

    const int px  = tid >> 3;
    const int chb = tid & 7;
    float part[7];
#pragma unroll
    for (int k = 0; k < 7; ++k) part[k] = 0.f;

    for (int chunk = 0; chunk < 4; ++chunk) {
        __syncthreads();
        for (int i = tid; i < 54 * 128; i += 256) {
            int ch = i >> 7, j = i & 127;
            wcs[ch * 130 + j] = (ch < 18) ? wcl[ch * 512 + chunk * 128 + j]
                                          : wrg[(ch - 18) * 512 + chunk * 128 + j];
        }
        __syncthreads();
        if (px < 24) {
            const float4* hv = (const float4*)(hsm + px * 520 + chunk * 128);
#pragma unroll 4
            for (int q = 0; q < 32; ++q) {
                float4 hq = hv[q];
#pragma unroll
                for (int k = 0; k < 7; ++k) {
                    int ch = chb * 7 + k;
                    if (ch < 54) {
                        float4 wq = *(const float4*)(wcs + ch * 130 + q * 4);
                        part[k] += hq.x * wq.x + hq.y * wq.y + hq.z * wq.z + hq.w * wq.w;
                    }
                }
            }
        }
    }
    if (px < 24) {
#pragma unroll
        for (int k = 0; k < 7; ++k) {
            int ch = chb * 7 + k;
            if (ch < 54) {
                float b = (ch < 18) ? bcl[ch] : brg[ch - 18];
                accum[(size_t)(gp0 + px) * NCH + ch] = part[k] + b;
            }
        }
    }
}

// ---------------------------------------------------------------------------
// decode: anchors + reg -> proposals/clipped boxes; cls -> d = c1-c0; histogram
// ---------------------------------------------------------------------------
__device__ __forceinline__ unsigned int key_of(float d) {
    unsigned int u = __float_as_uint(d);
    unsigned int k = (u & 0x80000000u) ? ~u : (u | 0x80000000u);  // asc in d
    return ~k;                                                     // asc key = desc d
}

__global__ void k_decode(const float* __restrict__ accum, const float* __restrict__ anchors,
                         float* __restrict__ props, float* __restrict__ boxes,
                         float* __restrict__ cls2, float* __restrict__ dval,
                         unsigned int* __restrict__ hist) {
    int idx = blockIdx.x * 256 + threadIdx.x;
    if (idx >= NA) return;
    int p = idx / 9, a = idx - p * 9;
    const float* ac = accum + p * NCH;
    float c0 = ac[2 * a], c1 = ac[2 * a + 1];
    float r0 = ac[18 + 4 * a + 0], r1 = ac[18 + 4 * a + 1];
    float r2 = ac[18 + 4 * a + 2], r3 = ac[18 + 4 * a + 3];
    const float* A = anchors + (size_t)idx * 4;
    float aw = A[2] - A[0] + 1.f, ah = A[3] - A[1] + 1.f;
    float ax = A[0] + 0.5f * (aw - 1.f), ay = A[1] + 0.5f * (ah - 1.f);
    float px = ax + aw * r0, py = ay + ah * r1;
    float pw = aw * expf(r2), ph = ah * expf(r3);
    float p0 = px - 0.5f * (pw - 1.f), p1 = py - 0.5f * (ph - 1.f);
    float p2 = px + 0.5f * (pw - 1.f), p3 = py + 0.5f * (ph - 1.f);
    props[idx * 4 + 0] = p0; props[idx * 4 + 1] = p1;
    props[idx * 4 + 2] = p2; props[idx * 4 + 3] = p3;
    boxes[idx * 4 + 0] = fminf(fmaxf(p0, 0.f), (float)(1536 - 1));
    boxes[idx * 4 + 1] = fminf(fmaxf(p1, 0.f), (float)(1536 - 1));
    boxes[idx * 4 + 2] = fminf(fmaxf(p2, 0.f), (float)(1536 - 1));
    boxes[idx * 4 + 3] = fminf(fmaxf(p3, 0.f), (float)(1536 - 1));
    cls2[idx * 2 + 0] = c0; cls2[idx * 2 + 1] = c1;
    float d = c1 - c0;
    dval[idx] = d;
    atomicAdd(&hist[key_of(d) >> 16], 1u);
}

// ---------------------------------------------------------------------------
// threshold: find histogram bin T containing rank-6000.
// R4: wave-reduce before LDS atomic (old: 64-way same-address LDS-atomic
// serialization, ~25us on one CU). shfl tree + 1 atomic per wave-iteration.
// ---------------------------------------------------------------------------
__global__ __launch_bounds__(1024) void k_thresh(const unsigned int* __restrict__ hist,
                                                 unsigned int* __restrict__ ctrl) {
    __shared__ unsigned int s[256];
    __shared__ unsigned int ss[256];
    __shared__ unsigned int chunkIdx, baseCount;
    const int tid = threadIdx.x;
    if (tid < 256) s[tid] = 0u;
    __syncthreads();
    for (int i = tid; i < 65536; i += 1024) {
        unsigned int v = hist[i];
#pragma unroll
        for (int d = 32; d > 0; d >>= 1) v += __shfl_down(v, d);
        if ((tid & 63) == 0) atomicAdd(&s[i >> 8], v);
    }
    __syncthreads();
    if (tid == 0) {
        unsigned int cum = 0; int c = 0;
        for (; c < 256; ++c) { if (cum + s[c] >= TOPN) break; cum += s[c]; }
        chunkIdx = (unsigned int)c; baseCount = cum;
    }
    __syncthreads();
    if (tid < 256) ss[tid] = hist[chunkIdx * 256 + tid];
    __syncthreads();
    if (tid == 0) {
        unsigned int cum = baseCount; int b = 0;
        for (; b < 256; ++b) { cum += ss[b]; if (cum >= TOPN) break; }
        ctrl[1] = chunkIdx * 256 + (unsigned int)b;  // T
        ctrl[2] = cum;
    }
}

// ---------------------------------------------------------------------------
// compact candidates (bin <= T): per-block LDS aggregation, 1 global atomic.
// ---------------------------------------------------------------------------
__global__ __launch_bounds__(256) void k_compact(const float* __restrict__ dval,
                                                 unsigned int* __restrict__ ctrl,
                                                 unsigned long long* __restrict__ cand) {
    __shared__ unsigned int cnt, base;
    const int tid = threadIdx.x;
    const int idx = blockIdx.x * 256 + tid;
    if (tid == 0) cnt = 0u;
    __syncthreads();
    unsigned int k2 = 0; bool pass = false; unsigned int pos = 0;
    if (idx < NA) {
        k2 = key_of(dval[idx]);
        pass = (k2 >> 16) <= ctrl[1];
        if (pass) pos = atomicAdd(&cnt, 1u);
    }
    __syncthreads();
    if (tid == 0) base = atomicAdd(&ctrl[0], cnt);
    __syncthreads();
    if (pass) {
        unsigned int p = base + pos;
        if (p < CAND_CAP) cand[p] = ((unsigned long long)k2 << 32) | (unsigned int)idx;
    }
}

// ---------------------------------------------------------------------------
// rank-by-count, j-range split 8 ways: block (ci,jq) ranks candidates
// ci*256..+256 against key slice jq*1024..+1024, WRITES partial rank to
// rankp[jq*CAND_CAP + i] (no atomics, no init).
// ---------------------------------------------------------------------------
__global__ __launch_bounds__(256) void k_rankp(const unsigned long long* __restrict__ cand,
                                               const unsigned int* __restrict__ ctrl,
                                               unsigned int* __restrict__ rankp) {
    __shared__ unsigned long long sc[RCHUNK];   // 8 KB
    const int tid = threadIdx.x;
    const int ci = blockIdx.x >> 3;            // candidate chunk 0..31
    const int jq = blockIdx.x & 7;             // j-slice 0..7
    unsigned int n = ctrl[0]; if (n > CAND_CAP) n = CAND_CAP;
    const int jb = jq * RCHUNK;
    for (int i = tid; i < RCHUNK; i += 256) {
        int j = jb + i;
        sc[i] = (j < (int)n) ? cand[j] : 0xFFFFFFFFFFFFFFFFull;  // pads never < mine
    }
    __syncthreads();
    const int i = ci * 256 + tid;
    // keep ALL lanes active through the shfl loop (inactive lanes would
    // poison __shfl reads for their wave-mates)
    const unsigned long long mine = (i < (int)n) ? cand[i] : 0xFFFFFFFFFFFFFFFFull;
    const int l = tid & 63;
    int nq = (int)n - jb; if (nq < 0) nq = 0; if (nq > RCHUNK) nq = RCHUNK;
    const int nr = (nq + 63) & ~63;
    int rank = 0;
    for (int j0 = 0; j0 < nr; j0 += 64) {
        unsigned long long kj = sc[j0 + l];
#pragma unroll
        for (int b = 0; b < 64; ++b) {
            unsigned long long kb = __shfl(kj, b);
            rank += (kb < mine) ? 1 : 0;
        }
    }
    if (i < (int)n) rankp[jq * CAND_CAP + i] = (unsigned int)rank;
}

// ---------------------------------------------------------------------------
// sum the 8 partial ranks, scatter boxes/probs at final rank.
// ---------------------------------------------------------------------------
__global__ __launch_bounds__(256) void k_ranks(const unsigned long long* __restrict__ cand,
                                               const unsigned int* __restrict__ ctrl,
                                               const unsigned int* __restrict__ rankp,
                                               const float* __restrict__ boxes,
                                               const float* __restrict__ dval,
                                               float* __restrict__ topBoxes,
                                               float* __restrict__ topProbs) {
    const int i = blockIdx.x * 256 + threadIdx.x;
    unsigned int n = ctrl[0]; if (n > CAND_CAP) n = CAND_CAP;
    if (i >= (int)n) return;
    unsigned int rank = 0;
#pragma unroll
    for (int q = 0; q < RQ; ++q) rank += rankp[q * CAND_CAP + i];
    if (rank < TOPN) {
        unsigned long long mine = cand[i];
        unsigned int idx = (unsigned int)mine;
        ((float4*)topBoxes)[rank] = ((const float4*)boxes)[idx];
        topProbs[rank] = 1.f / (1.f + expf(-dval[idx]));
    }
}

// ---------------------------------------------------------------------------
// NMS suppression bitmask, triangular grid.
// R4: c-block's 64 boxes staged in LDS once per block (was 64 VMEM loads
// per lane); whole-block early-out for fully-dead triangular blocks.
// ---------------------------------------------------------------------------
__global__ __launch_bounds__(256) void k_mask(const float* __restrict__ topBoxes,
                                              unsigned long long* __restrict__ mask) {
    const int c = blockIdx.y;
    if (c < blockIdx.x * 4) return;            // whole block below diagonal
    __shared__ float4 bsh[64];
    const int tid = threadIdx.x;
    const int i = blockIdx.x * 256 + tid;
    if (tid < 64) {
        int j = c * 64 + tid;
        float4 bv = {0.f, 0.f, 0.f, 0.f};
        if (j < TOPN) bv = ((const float4*)topBoxes)[j];
        bsh[tid] = bv;
    }
    __syncthreads();
    if (i >= TOPN || c < (i >> 6)) return;
    float4 bi = ((const float4*)topBoxes)[i];
    float ai = (bi.z - bi.x + 1.f) * (bi.w - bi.y + 1.f);
    unsigned long long m = 0;
    int j0 = c * 64;
    for (int b = 0; b < 64; ++b) {
        int j = j0 + b;
        if (j >= TOPN || j <= i) continue;
        float4 bj = bsh[b];
        float aj = (bj.z - bj.x + 1.f) * (bj.w - bj.y + 1.f);
        float iw = fmaxf(fminf(bi.z, bj.z) - fmaxf(bi.x, bj.x) + 1.f, 0.f);
        float ih = fmaxf(fminf(bi.w, bj.w) - fmaxf(bi.y, bj.y) + 1.f, 0.f);
        float inter = iw * ih;
        float iou = inter / (ai + aj - inter);
        if (iou > 0.7f) m |= (1ull << b);
    }
    mask[(size_t)i * NW + c] = m;
}

// ---------------------------------------------------------------------------
// greedy scan, single wave, batched unconditional loads, early exit at 300.
// [R3-proven version. The R4 256-thread restructure coincided with a device
// abort; reverted pending isolation.]
// ---------------------------------------------------------------------------
__global__ __launch_bounds__(64) void k_scan(const unsigned long long* __restrict__ mask,
                                             const float* __restrict__ topBoxes,
                                             const float* __restrict__ topProbs,
                                             float* __restrict__ out2, float* __restrict__ out3) {
    __shared__ unsigned long long kw[NW];
    int l = threadIdx.x;
    for (int i = l; i < NW; i += 64)
        kw[i] = (i == NW - 1) ? 0x0000FFFFFFFFFFFFull : ~0ull;  // 6000 = 93*64+48
    __syncthreads();
    int kept = 0;
    for (int c = 0; c < NW && kept < POSN; ++c) {
        unsigned long long w = kw[c];
        unsigned long long m = mask[(size_t)(c * 64 + l) * NW + c];
        for (int b = 0; b < 64; ++b) {
            if ((w >> b) & 1ull) {
                unsigned long long mb = __shfl(m, b);
                w &= ~mb;
            }
        }
        if ((w >> l) & 1ull) {
            int r = kept + __popcll(w & ((1ull << l) - 1ull));
            if (r < POSN) {
                int j = c * 64 + l;
                out2[r * 4 + 0] = topBoxes[j * 4 + 0];
                out2[r * 4 + 1] = topBoxes[j * 4 + 1];
                out2[r * 4 + 2] = topBoxes[j * 4 + 2];
                out2[r * 4 + 3] = topBoxes[j * 4 + 3];
                out3[r] = topProbs[j];
            }
        }
        kept += __popcll(w);
        if (kept >= POSN) break;
        for (int c2 = c + 1 + l; c2 < NW; c2 += 64) {
            unsigned long long sup = 0;
#pragma unroll
            for (int b0 = 0; b0 < 64; b0 += 16) {
                unsigned long long t[16];
#pragma unroll
                for (int j = 0; j < 16; ++j)
                    t[j] = mask[(size_t)(c * 64 + b0 + j) * NW + c2];
#pragma unroll
                for (int j = 0; j < 16; ++j)
                    sup |= ((w >> (b0 + j)) & 1ull) ? t[j] : 0ull;
            }
            kw[c2] &= ~sup;
        }
        __syncthreads();
    }
    for (int r = kept + l; r < POSN; r += 64) {
        out2[r * 4 + 0] = 0.f; out2[r * 4 + 1] = 0.f;
        out2[r * 4 + 2] = 0.f; out2[r * 4 + 3] = 0.f;
        out3[r] = 0.f;
    }
}

// ---------------------------------------------------------------------------
// gather proposals/cls at valid_idx
// ---------------------------------------------------------------------------
__global__ void k_gather(const int* __restrict__ vidx, const float* __restrict__ props,
                         const float* __restrict__ cls2, float* __restrict__ out0,
                         float* __restrict__ out1, int nv) {
    int i = blockIdx.x * 256 + threadIdx.x;
    if (i >= nv) return;
    int v = vidx[i];
    ((float4*)out0)[i] = ((const float4*)props)[v];
    ((float2*)out1)[i] = ((const float2*)cls2)[v];
}

// ---------------------------------------------------------------------------
extern "C" void kernel_launch(void* const* d_in, const int* in_sizes, int n_in,
                              void* d_out, int out_size, void* d_ws, size_t ws_size,
                              hipStream_t stream) {
    const float* x       = (const float*)d_in[0];
    const float* w_rpn   = (const float*)d_in[1];
    const float* b_rpn   = (const float*)d_in[2];
    const float* w_cls   = (const float*)d_in[3];
    const float* b_cls   = (const float*)d_in[4];
    const float* w_reg   = (const float*)d_in[5];
    const float* b_reg   = (const float*)d_in[6];
    const float* anchors = (const float*)d_in[7];
    const int*   vidx    = (const int*)d_in[8];
    const int nv = in_sizes[8];

    char* ws = (char*)d_ws;
    float* accum            = (float*)(ws + 0);
    float* props            = (float*)(ws + 1990656);
    float* boxes            = (float*)(ws + 3317760);
    float* cls2             = (float*)(ws + 4644864);
    float* dval             = (float*)(ws + 5308416);
    unsigned int* hist      = (unsigned int*)(ws + 5640192);
    unsigned int* ctrl      = (unsigned int*)(ws + 5902336);
    unsigned long long* cand = (unsigned long long*)(ws + 5902400);
    float* topBoxes         = (float*)(ws + 5967936);
    float* topProbs         = (float*)(ws + 6063936);
    unsigned long long* mask = (unsigned long long*)(ws + 6087936);  // 4.512 MB
    _Float16* xt_h          = (_Float16*)(ws + 10599936);  // 18.87 MB
    _Float16* xt_l          = (_Float16*)(ws + 29474304);  // 18.87 MB
    _Float16* wt2           = (_Float16*)(ws + 48348672);  // 18.87 MB fragment-ordered
    float* hp               = (float*)(ws + 67223040);     // 75.5 MB (4 K-splits; ends ~143 MB)
    // partial ranks (8 x 8192 u32 = 256 KB) aliased onto xt_h's region:
    // xt_h is dead after k_conv, and k_rankp runs strictly after it.
    unsigned int* rankp     = (unsigned int*)(ws + 10599936);

    float* out0 = (float*)d_out;
    float* out1 = out0 + (size_t)nv * 4;
    float* out2 = out1 + (size_t)nv * 2;
    float* out3 = out2 + (size_t)POSN * 4;

    k_init<<<(65536 + 16 + 255) / 256, 256, 0, stream>>>(hist, ctrl);
    k_xtr<<<dim3(144, 16), 256, 0, stream>>>(x, xt_h, xt_l);
    k_wtr<<<dim3(4, 32, 4), 256, 0, stream>>>(w_rpn, wt2);
    k_conv<<<1536, 512, 0, stream>>>(xt_h, xt_l, wt2, hp);
    k_post<<<384, 256, 0, stream>>>(hp, b_rpn, w_cls, w_reg, b_cls, b_reg, accum);
    k_decode<<<(NA + 255) / 256, 256, 0, stream>>>(accum, anchors, props, boxes, cls2, dval, hist);
    k_thresh<<<1, 1024, 0, stream>>>(hist, ctrl);
    k_compact<<<(NA + 255) / 256, 256, 0, stream>>>(dval, ctrl, cand);
    k_rankp<<<32 * RQ, 256, 0, stream>>>(cand, ctrl, rankp);
    k_ranks<<<32, 256, 0, stream>>>(cand, ctrl, rankp, boxes, dval, topBoxes, topProbs);
    k_mask<<<dim3(24, NW), 256, 0, stream>>>(topBoxes, mask);
    k_scan<<<1, 64, 0, stream>>>(mask, topBoxes, topProbs, out2, out3);
    k_gather<<<(nv + 255) / 256, 256, 0, stream>>>(vidx, props, cls2, out0, out1, nv);
}

// Round 8
// 639.827 us; speedup vs baseline: 1.1312x; 1.0872x over previous
//
#include <hip/hip_runtime.h>

#define H 96
#define W 96
#define CIN 1024
#define NPIX 9216          // 96*96
#define NCH 54             // 18 cls + 36 reg channels
#define NA 82944           // 9216*9 anchors
#define TOPN 6000
#define NW 94              // ceil(6000/64)
#define POSN 300
#define CAND_CAP 8192
#define RQ 8               // k_rank j-range split factor
#define RCHUNK 1024        // CAND_CAP / RQ

typedef _Float16 half8_t __attribute__((ext_vector_type(8)));
typedef float f32x4 __attribute__((ext_vector_type(4)));

#define CIP 40             // padded ci stride in halves (80 B: 16B-aligned, 2-way banks = free)
#define XS_PLANE 11760     // 3*98*40 halves
#define HP_SPLIT 4718592   // 4*9216*128 floats per K-split buffer

// ---------------------------------------------------------------------------
// init: hist/ctrl <- 0
// ---------------------------------------------------------------------------
__global__ void k_init(unsigned int* __restrict__ hist, unsigned int* __restrict__ ctrl) {
    int t = blockIdx.x * 256 + threadIdx.x;
    if (t < 65536) hist[t] = 0u;
    else if (t < 65536 + 16) ctrl[t - 65536] = 0u;
}

// ---------------------------------------------------------------------------
// x transpose + fp16 split: x[ci][px] fp32 -> xt_h[px][ci], xt_l[px][ci]
// half8 (16B/lane) vectorized stores.
// ---------------------------------------------------------------------------
__global__ __launch_bounds__(256) void k_xtr(const float* __restrict__ x,
                                             _Float16* __restrict__ xh,
                                             _Float16* __restrict__ xl) {
    __shared__ float t[64 * 65];
    const int tid = threadIdx.x;
    const int px0 = blockIdx.x * 64, ci0 = blockIdx.y * 64;
    for (int i = tid; i < 4096; i += 256) {
        int ci = i >> 6, px = i & 63;
        t[ci * 65 + px] = x[(size_t)(ci0 + ci) * NPIX + px0 + px];
    }
    __syncthreads();
    for (int i = tid; i < 512; i += 256) {     // 64 px x 8 ci-octets
        int px = i >> 3, q = i & 7;
        _Float16 h8[8], l8[8];
#pragma unroll
        for (int j = 0; j < 8; ++j) {
            float v = t[(q * 8 + j) * 65 + px];
            _Float16 h = (_Float16)v;
            h8[j] = h;
            l8[j] = (_Float16)((v - (float)h) * 2048.f);
        }
        size_t o = (size_t)(px0 + px) * 1024 + ci0 + q * 8;
        *(half8_t*)(xh + o) = *(half8_t*)h8;
        *(half8_t*)(xl + o) = *(half8_t*)l8;
    }
}

// ---------------------------------------------------------------------------
// weight transform to MFMA-fragment order + fp16 split (coalesced).
// R4: g-loop split onto blockIdx.z -> 512 blocks (was 128; half the GPU idle).
// ---------------------------------------------------------------------------
__global__ __launch_bounds__(256) void k_wtr(const float* __restrict__ wr,
                                             _Float16* __restrict__ wt2) {
    __shared__ float tile[32 * 292];
    const int cb = blockIdx.x, cc = blockIdx.y, g = blockIdx.z;
    const int tid = threadIdx.x;
    for (int i = tid; i < 32 * 288; i += 256) {
        int row = i / 288, col = i - row * 288;
        tile[row * 292 + col] = wr[(size_t)(cb * 128 + g * 32 + row) * 9216 + cc * 288 + col];
    }
    __syncthreads();
#pragma unroll
    for (int k = 0; k < 9; ++k) {
        int G = k * 256 + tid;           // < 2304
        int tap = G >> 8, r = G & 255;
        int pl = r >> 7, ntl = (r >> 6) & 1, l = r & 63;
        int co_loc = ntl * 16 + (l & 15);
        int ci_b = (l >> 4) * 8;
        _Float16 o8[8];
#pragma unroll
        for (int j = 0; j < 8; ++j) {
            float v = tile[co_loc * 292 + (ci_b + j) * 9 + tap];
            _Float16 h = (_Float16)v;
            o8[j] = pl ? (_Float16)((v - (float)h) * 2048.f) : h;
        }
        _Float16* dst = wt2 + ((size_t)((tap * 4 + cb) * 32 + cc)) * 8192 +
                        (size_t)(pl * 8 + (g * 2 + ntl)) * 512 + l * 8;
        *(half8_t*)dst = *(half8_t*)o8;
    }
}

// ---------------------------------------------------------------------------
// MFMA implicit-GEMM conv3x3(1024->512), K-split by 4.
// fp16 2-plane split: h = Ah*Bh + (Ah*Bl' + Al'*Bh)/2048.
//
// R8: 8-WAVE / 512-THREAD, NO B-PREFETCH (TLP replaces ILP).
// Register-residency ledger (unified 512 regs/lane/SIMD, gfx950):
//   R5 4-wave: 128 VGPR + 96 AGPR = 224/wave -> 2 waves/SIMD (21% occ)
//   R6 (512,4): cap 64 -> SPILL (FETCH 534 MB) but 2 blocks resident
//               at 64+48=112/wave (44.6% occ) => 112 fits 4 waves/SIMD
//   R7 (512,2): 80+48=128/wave -> ONLY 1 block resident (23.2% occ)
//               => residency threshold is BETWEEN 112 and 128 total.
// R8 removes the B-tap-prefetch regs (bnh/bnl + copies, ~8-16 VGPR) to
// land ~64-72 VGPR + 48 AGPR = 112-120/wave -> 4 waves/SIMD -> 2 blocks.
// B loaded directly per tap: at 4 waves/SIMD the ~200cyc L2-hit latency
// is hidden by sibling waves' MFMAs (TLP), which R1-era 2-waves/SIMD
// could not do (that's why prefetch existed).
// launch_bounds 2nd arg = MIN BLOCKS PER CU (CUDA semantics, proven
// R6/R7); (512,2) => VGPR cap 128, no spill at ~70.
// Grid 1536 = 3 exact residency rounds at 2 blocks/CU.
//
// Y-BAND XCD SWIZZLE: with round-robin bid%8 -> XCD dispatch, XCD k gets
// rows [12k,12k+12) for ALL (cb,ks).
// Epilogue LDS tile padded 96x132 f32 (breaks 4-way store bank conflict).
// ---------------------------------------------------------------------------
__global__ __launch_bounds__(512, 2) void k_conv(
    const _Float16* __restrict__ xth, const _Float16* __restrict__ xtl,
    const _Float16* __restrict__ wt2, float* __restrict__ hp) {
    __shared__ __align__(16) char smem[50688];   // xs 47040 B; epilogue 96x132 f32
    _Float16* xs = (_Float16*)smem;

    const int tid = threadIdx.x;
    const int bid = blockIdx.x;
    const int xcd = bid & 7;
    const int i8  = bid >> 3;          // 0..191
    const int y   = xcd * 12 + (i8 % 12);
    const int cbks = i8 / 12;          // 0..15
    const int cb  = cbks & 3;          // co block of 128
    const int ks  = cbks >> 2;         // K-split quarter (0..3)
    const int l  = tid & 63;
    const int wv = tid >> 6;          // 0..7
    const int mg = wv & 1;            // m-group (0..1): px half
    const int ng = wv >> 1;           // n-group (0..3): co quarter
    const int lm = l & 15;
    const int lk = l >> 4;            // 0..3

    f32x4 acc_h[3][2];
    f32x4 acc_x[3][2];
#pragma unroll
    for (int m2 = 0; m2 < 3; ++m2)
#pragma unroll
        for (int nt = 0; nt < 2; ++nt) {
            acc_h[m2][nt] = (f32x4){0.f, 0.f, 0.f, 0.f};
            acc_x[m2][nt] = (f32x4){0.f, 0.f, 0.f, 0.f};
        }

    // zero px pad columns (pxp = 0 and 97), both planes, 3 rows
    if (tid < 480) {
        int pl = tid / 240, j = tid - pl * 240;
        int r = j / 80, j2 = j - r * 80;
        int side = j2 / 40, c = j2 - side * 40;
        xs[pl * XS_PLANE + (r * 98 + side * 97) * CIP + c] = (_Float16)0.f;
    }

    // 2304 float4 items (2 planes x 3 rows x 96 px x 4 quads) over 512 thr
    auto ldx = [&](float4* xr, int cc_) {
#pragma unroll
        for (int k = 0; k < 5; ++k) {
            int item = k * 512 + tid;
            if (item < 2304) {
                int pl = (item >= 1152) ? 1 : 0;
                int j = item - pl * 1152;
                int r = j / 384, j2 = j - r * 384;
                int px = j2 >> 2, q = j2 & 3;
                int yy = y + r - 1;
                float4 v = {0.f, 0.f, 0.f, 0.f};
                if (yy >= 0 && yy < H)
                    v = *(const float4*)((pl ? xtl : xth) + (size_t)(yy * 96 + px) * 1024 + cc_ * 32 + q * 8);
                xr[k] = v;
            }
        }
    };
    auto stx = [&](const float4* xr) {
#pragma unroll
        for (int k = 0; k < 5; ++k) {
            int item = k * 512 + tid;
            if (item < 2304) {
                int pl = (item >= 1152) ? 1 : 0;
                int j = item - pl * 1152;
                int r = j / 384, j2 = j - r * 384;
                int px = j2 >> 2, q = j2 & 3;
                *(float4*)(xs + pl * XS_PLANE + (r * 98 + px + 1) * CIP + q * 8) = xr[k];
            }
        }
    };
    auto ldb = [&](half8_t* bh, half8_t* bl, int cc_, int tap_) {
        const _Float16* base = wt2 + ((size_t)((tap_ * 4 + cb) * 32 + cc_) * 16) * 512 + (size_t)l * 8;
#pragma unroll
        for (int nt = 0; nt < 2; ++nt) {
            bh[nt] = *(const half8_t*)(base + (size_t)(ng * 2 + nt) * 512);
            bl[nt] = *(const half8_t*)(base + (size_t)(8 + ng * 2 + nt) * 512);
        }
    };

    const int cc0 = ks * 8;
    const int ccE = cc0 + 8;
    float4 xr[5];
    ldx(xr, cc0);

    for (int cc = cc0; cc < ccE; ++cc) {
        __syncthreads();           // previous chunk's xs reads complete
        stx(xr);
        __syncthreads();           // xs visible
        const int ccn = (cc + 1 < ccE) ? cc + 1 : cc;
        ldx(xr, ccn);              // prefetch next chunk's x (in flight during taps)

#pragma unroll
        for (int tap = 0; tap < 9; ++tap) {
            half8_t bh[2], bl[2];
            ldb(bh, bl, cc, tap);   // direct load; latency hidden by sibling waves (TLP)

            const int ky = tap / 3, kx = tap - 3 * (tap / 3);
            half8_t ah[3], al[3];
#pragma unroll
            for (int m2 = 0; m2 < 3; ++m2) {
                const int pxp = (mg * 3 + m2) * 16 + lm + kx;
                ah[m2] = *(const half8_t*)(xs + (ky * 98 + pxp) * CIP + lk * 8);
                al[m2] = *(const half8_t*)(xs + XS_PLANE + (ky * 98 + pxp) * CIP + lk * 8);
            }
#pragma unroll
            for (int m2 = 0; m2 < 3; ++m2)
#pragma unroll
                for (int nt = 0; nt < 2; ++nt)
                    acc_h[m2][nt] = __builtin_amdgcn_mfma_f32_16x16x32_f16(ah[m2], bh[nt], acc_h[m2][nt], 0, 0, 0);
#pragma unroll
            for (int m2 = 0; m2 < 3; ++m2)
#pragma unroll
                for (int nt = 0; nt < 2; ++nt)
                    acc_x[m2][nt] = __builtin_amdgcn_mfma_f32_16x16x32_f16(ah[m2], bl[nt], acc_x[m2][nt], 0, 0, 0);
#pragma unroll
            for (int m2 = 0; m2 < 3; ++m2)
#pragma unroll
                for (int nt = 0; nt < 2; ++nt)
                    acc_x[m2][nt] = __builtin_amdgcn_mfma_f32_16x16x32_f16(al[m2], bh[nt], acc_x[m2][nt], 0, 0, 0);
        }
    }

    // ---- epilogue: combine planes, bounce through LDS, coalesced store ----
    __syncthreads();
    float* cs = (float*)smem;
#pragma unroll
    for (int m2 = 0; m2 < 3; ++m2)
#pragma unroll
        for (int nt = 0; nt < 2; ++nt) {
            int co = (ng * 2 + nt) * 16 + lm;
#pragma unroll
            for (int r = 0; r < 4; ++r) {
                int px = (mg * 3 + m2) * 16 + lk * 4 + r;
                cs[px * 132 + co] = acc_h[m2][nt][r] + acc_x[m2][nt][r] * (1.f / 2048.f);
            }
        }
    __syncthreads();
    float4* dst = (float4*)(hp + ((size_t)(ks * 4 + cb) * NPIX + y * 96) * 128);
    for (int i = tid; i < 3072; i += 512) {
        int px = i >> 5, c4 = i & 31;
        dst[i] = *(const float4*)(cs + px * 132 + c4 * 4);
    }
}

// ---------------------------------------------------------------------------
// post: h = relu(hp0+hp1+hp2+hp3+b_rpn) staged in LDS; 1x1 convs (54 ch).
// ---------------------------------------------------------------------------
__global__ __launch_bounds__(256, 2) void k_post(const float* __restrict__ hp,
                                                 const float* __restrict__ br,
                                                 const float* __restrict__ wcl,
                                                 const float* __restrict__ wrg,
                                                 const float* __restrict__ bcl,
                                                 const float* __restrict__ brg,
                                                 float* __restrict__ accum) {
    __shared__ float hsm[24 * 520];
    __shared__ float wcs[54 * 130];
    const int tid = threadIdx.x;
    const int gp0 = blockIdx.x * 24;

    for (int i = tid; i < 24 * 512; i += 256) {
        int px = i >> 9, ci = i & 511;
        int cbk = ci >> 7, co = ci & 127;
        size_t off = ((size_t)cbk * NPIX + gp0 + px) * 128 + co;
        float v = hp[off] + hp[off + HP_SPLIT] + hp[off + 2 * (size_t)HP_SPLIT] +
                  hp[off + 3 * (size_t)HP_SPLIT] + br[ci];
        hsm[px * 520 + ci] = fmaxf(v, 0.f);
    }

    const int px  = tid >> 3;
    const int chb = tid & 7;
    float part[7];
#pragma unroll
    for (int k = 0; k < 7; ++k) part[k] = 0.f;

    for (int chunk = 0; chunk < 4; ++chunk) {
        __syncthreads();
        for (int i = tid; i < 54 * 128; i += 256) {
            int ch = i >> 7, j = i & 127;
            wcs[ch * 130 + j] = (ch < 18) ? wcl[ch * 512 + chunk * 128 + j]
                                          : wrg[(ch - 18) * 512 + chunk * 128 + j];
        }
        __syncthreads();
        if (px < 24) {
            const float4* hv = (const float4*)(hsm + px * 520 + chunk * 128);
#pragma unroll 4
            for (int q = 0; q < 32; ++q) {
                float4 hq = hv[q];
#pragma unroll
                for (int k = 0; k < 7; ++k) {
                    int ch = chb * 7 + k;
                    if (ch < 54) {
                        float4 wq = *(const float4*)(wcs + ch * 130 + q * 4);
                        part[k] += hq.x * wq.x + hq.y * wq.y + hq.z * wq.z + hq.w * wq.w;
                    }
                }
            }
        }
    }
    if (px < 24) {
#pragma unroll
        for (int k = 0; k < 7; ++k) {
            int ch = chb * 7 + k;
            if (ch < 54) {
                float b = (ch < 18) ? bcl[ch] : brg[ch - 18];
                accum[(size_t)(gp0 + px) * NCH + ch] = part[k] + b;
            }
        }
    }
}

// ---------------------------------------------------------------------------
// decode: anchors + reg -> proposals/clipped boxes; cls -> d = c1-c0; histogram
// ---------------------------------------------------------------------------
__device__ __forceinline__ unsigned int key_of(float d) {
    unsigned int u = __float_as_uint(d);
    unsigned int k = (u & 0x80000000u) ? ~u : (u | 0x80000000u);  // asc in d
    return ~k;                                                     // asc key = desc d
}

__global__ void k_decode(const float* __restrict__ accum, const float* __restrict__ anchors,
                         float* __restrict__ props, float* __restrict__ boxes,
                         float* __restrict__ cls2, float* __restrict__ dval,
                         unsigned int* __restrict__ hist) {
    int idx = blockIdx.x * 256 + threadIdx.x;
    if (idx >= NA) return;
    int p = idx / 9, a = idx - p * 9;
    const float* ac = accum + p * NCH;
    float c0 = ac[2 * a], c1 = ac[2 * a + 1];
    float r0 = ac[18 + 4 * a + 0], r1 = ac[18 + 4 * a + 1];
    float r2 = ac[18 + 4 * a + 2], r3 = ac[18 + 4 * a + 3];
    const float* A = anchors + (size_t)idx * 4;
    float aw = A[2] - A[0] + 1.f, ah = A[3] - A[1] + 1.f;
    float ax = A[0] + 0.5f * (aw - 1.f), ay = A[1] + 0.5f * (ah - 1.f);
    float px = ax + aw * r0, py = ay + ah * r1;
    float pw = aw * expf(r2), ph = ah * expf(r3);
    float p0 = px - 0.5f * (pw - 1.f), p1 = py - 0.5f * (ph - 1.f);
    float p2 = px + 0.5f * (pw - 1.f), p3 = py + 0.5f * (ph - 1.f);
    props[idx * 4 + 0] = p0; props[idx * 4 + 1] = p1;
    props[idx * 4 + 2] = p2; props[idx * 4 + 3] = p3;
    boxes[idx * 4 + 0] = fminf(fmaxf(p0, 0.f), (float)(1536 - 1));
    boxes[idx * 4 + 1] = fminf(fmaxf(p1, 0.f), (float)(1536 - 1));
    boxes[idx * 4 + 2] = fminf(fmaxf(p2, 0.f), (float)(1536 - 1));
    boxes[idx * 4 + 3] = fminf(fmaxf(p3, 0.f), (float)(1536 - 1));
    cls2[idx * 2 + 0] = c0; cls2[idx * 2 + 1] = c1;
    float d = c1 - c0;
    dval[idx] = d;
    atomicAdd(&hist[key_of(d) >> 16], 1u);
}

// ---------------------------------------------------------------------------
// threshold: find histogram bin T containing rank-6000.
// R4: wave-reduce before LDS atomic (old: 64-way same-address LDS-atomic
// serialization, ~25us on one CU). shfl tree + 1 atomic per wave-iteration.
// ---------------------------------------------------------------------------
__global__ __launch_bounds__(1024) void k_thresh(const unsigned int* __restrict__ hist,
                                                 unsigned int* __restrict__ ctrl) {
    __shared__ unsigned int s[256];
    __shared__ unsigned int ss[256];
    __shared__ unsigned int chunkIdx, baseCount;
    const int tid = threadIdx.x;
    if (tid < 256) s[tid] = 0u;
    __syncthreads();
    for (int i = tid; i < 65536; i += 1024) {
        unsigned int v = hist[i];
#pragma unroll
        for (int d = 32; d > 0; d >>= 1) v += __shfl_down(v, d);
        if ((tid & 63) == 0) atomicAdd(&s[i >> 8], v);
    }
    __syncthreads();
    if (tid == 0) {
        unsigned int cum = 0; int c = 0;
        for (; c < 256; ++c) { if (cum + s[c] >= TOPN) break; cum += s[c]; }
        chunkIdx = (unsigned int)c; baseCount = cum;
    }
    __syncthreads();
    if (tid < 256) ss[tid] = hist[chunkIdx * 256 + tid];
    __syncthreads();
    if (tid == 0) {
        unsigned int cum = baseCount; int b = 0;
        for (; b < 256; ++b) { cum += ss[b]; if (cum >= TOPN) break; }
        ctrl[1] = chunkIdx * 256 + (unsigned int)b;  // T
        ctrl[2] = cum;
    }
}

// ---------------------------------------------------------------------------
// compact candidates (bin <= T): per-block LDS aggregation, 1 global atomic.
// ---------------------------------------------------------------------------
__global__ __launch_bounds__(256) void k_compact(const float* __restrict__ dval,
                                                 unsigned int* __restrict__ ctrl,
                                                 unsigned long long* __restrict__ cand) {
    __shared__ unsigned int cnt, base;
    const int tid = threadIdx.x;
    const int idx = blockIdx.x * 256 + tid;
    if (tid == 0) cnt = 0u;
    __syncthreads();
    unsigned int k2 = 0; bool pass = false; unsigned int pos = 0;
    if (idx < NA) {
        k2 = key_of(dval[idx]);
        pass = (k2 >> 16) <= ctrl[1];
        if (pass) pos = atomicAdd(&cnt, 1u);
    }
    __syncthreads();
    if (tid == 0) base = atomicAdd(&ctrl[0], cnt);
    __syncthreads();
    if (pass) {
        unsigned int p = base + pos;
        if (p < CAND_CAP) cand[p] = ((unsigned long long)k2 << 32) | (unsigned int)idx;
    }
}

// ---------------------------------------------------------------------------
// rank-by-count, j-range split 8 ways: block (ci,jq) ranks candidates
// ci*256..+256 against key slice jq*1024..+1024, WRITES partial rank to
// rankp[jq*CAND_CAP + i] (no atomics, no init).
// ---------------------------------------------------------------------------
__global__ __launch_bounds__(256) void k_rankp(const unsigned long long* __restrict__ cand,
                                               const unsigned int* __restrict__ ctrl,
                                               unsigned int* __restrict__ rankp) {
    __shared__ unsigned long long sc[RCHUNK];   // 8 KB
    const int tid = threadIdx.x;
    const int ci = blockIdx.x >> 3;            // candidate chunk 0..31
    const int jq = blockIdx.x & 7;             // j-slice 0..7
    unsigned int n = ctrl[0]; if (n > CAND_CAP) n = CAND_CAP;
    const int jb = jq * RCHUNK;
    for (int i = tid; i < RCHUNK; i += 256) {
        int j = jb + i;
        sc[i] = (j < (int)n) ? cand[j] : 0xFFFFFFFFFFFFFFFFull;  // pads never < mine
    }
    __syncthreads();
    const int i = ci * 256 + tid;
    // keep ALL lanes active through the shfl loop (inactive lanes would
    // poison __shfl reads for their wave-mates)
    const unsigned long long mine = (i < (int)n) ? cand[i] : 0xFFFFFFFFFFFFFFFFull;
    const int l = tid & 63;
    int nq = (int)n - jb; if (nq < 0) nq = 0; if (nq > RCHUNK) nq = RCHUNK;
    const int nr = (nq + 63) & ~63;
    int rank = 0;
    for (int j0 = 0; j0 < nr; j0 += 64) {
        unsigned long long kj = sc[j0 + l];
#pragma unroll
        for (int b = 0; b < 64; ++b) {
            unsigned long long kb = __shfl(kj, b);
            rank += (kb < mine) ? 1 : 0;
        }
    }
    if (i < (int)n) rankp[jq * CAND_CAP + i] = (unsigned int)rank;
}

// ---------------------------------------------------------------------------
// sum the 8 partial ranks, scatter boxes/probs at final rank.
// ---------------------------------------------------------------------------
__global__ __launch_bounds__(256) void k_ranks(const unsigned long long* __restrict__ cand,
                                               const unsigned int* __restrict__ ctrl,
                                               const unsigned int* __restrict__ rankp,
                                               const float* __restrict__ boxes,
                                               const float* __restrict__ dval,
                                               float* __restrict__ topBoxes,
                                               float* __restrict__ topProbs) {
    const int i = blockIdx.x * 256 + threadIdx.x;
    unsigned int n = ctrl[0]; if (n > CAND_CAP) n = CAND_CAP;
    if (i >= (int)n) return;
    unsigned int rank = 0;
#pragma unroll
    for (int q = 0; q < RQ; ++q) rank += rankp[q * CAND_CAP + i];
    if (rank < TOPN) {
        unsigned long long mine = cand[i];
        unsigned int idx = (unsigned int)mine;
        ((float4*)topBoxes)[rank] = ((const float4*)boxes)[idx];
        topProbs[rank] = 1.f / (1.f + expf(-dval[idx]));
    }
}

// ---------------------------------------------------------------------------
// NMS suppression bitmask, triangular grid.
// R4: c-block's 64 boxes staged in LDS once per block (was 64 VMEM loads
// per lane); whole-block early-out for fully-dead triangular blocks.
// ---------------------------------------------------------------------------
__global__ __launch_bounds__(256) void k_mask(const float* __restrict__ topBoxes,
                                              unsigned long long* __restrict__ mask) {
    const int c = blockIdx.y;
    if (c < blockIdx.x * 4) return;            // whole block below diagonal
    __shared__ float4 bsh[64];
    const int tid = threadIdx.x;
    const int i = blockIdx.x * 256 + tid;
    if (tid < 64) {
        int j = c * 64 + tid;
        float4 bv = {0.f, 0.f, 0.f, 0.f};
        if (j < TOPN) bv = ((const float4*)topBoxes)[j];
        bsh[tid] = bv;
    }
    __syncthreads();
    if (i >= TOPN || c < (i >> 6)) return;
    float4 bi = ((const float4*)topBoxes)[i];
    float ai = (bi.z - bi.x + 1.f) * (bi.w - bi.y + 1.f);
    unsigned long long m = 0;
    int j0 = c * 64;
    for (int b = 0; b < 64; ++b) {
        int j = j0 + b;
        if (j >= TOPN || j <= i) continue;
        float4 bj = bsh[b];
        float aj = (bj.z - bj.x + 1.f) * (bj.w - bj.y + 1.f);
        float iw = fmaxf(fminf(bi.z, bj.z) - fmaxf(bi.x, bj.x) + 1.f, 0.f);
        float ih = fmaxf(fminf(bi.w, bj.w) - fmaxf(bi.y, bj.y) + 1.f, 0.f);
        float inter = iw * ih;
        float iou = inter / (ai + aj - inter);
        if (iou > 0.7f) m |= (1ull << b);
    }
    mask[(size_t)i * NW + c] = m;
}

// ---------------------------------------------------------------------------
// greedy scan, single wave, batched unconditional loads, early exit at 300.
// [R3-proven version. The R4 256-thread restructure coincided with a device
// abort; reverted pending isolation.]
// ---------------------------------------------------------------------------
__global__ __launch_bounds__(64) void k_scan(const unsigned long long* __restrict__ mask,
                                             const float* __restrict__ topBoxes,
                                             const float* __restrict__ topProbs,
                                             float* __restrict__ out2, float* __restrict__ out3) {
    __shared__ unsigned long long kw[NW];
    int l = threadIdx.x;
    for (int i = l; i < NW; i += 64)
        kw[i] = (i == NW - 1) ? 0x0000FFFFFFFFFFFFull : ~0ull;  // 6000 = 93*64+48
    __syncthreads();
    int kept = 0;
    for (int c = 0; c < NW && kept < POSN; ++c) {
        unsigned long long w = kw[c];
        unsigned long long m = mask[(size_t)(c * 64 + l) * NW + c];
        for (int b = 0; b < 64; ++b) {
            if ((w >> b) & 1ull) {
                unsigned long long mb = __shfl(m, b);
                w &= ~mb;
            }
        }
        if ((w >> l) & 1ull) {
            int r = kept + __popcll(w & ((1ull << l) - 1ull));
            if (r < POSN) {
                int j = c * 64 + l;
                out2[r * 4 + 0] = topBoxes[j * 4 + 0];
                out2[r * 4 + 1] = topBoxes[j * 4 + 1];
                out2[r * 4 + 2] = topBoxes[j * 4 + 2];
                out2[r * 4 + 3] = topBoxes[j * 4 + 3];
                out3[r] = topProbs[j];
            }
        }
        kept += __popcll(w);
        if (kept >= POSN) break;
        for (int c2 = c + 1 + l; c2 < NW; c2 += 64) {
            unsigned long long sup = 0;
#pragma unroll
            for (int b0 = 0; b0 < 64; b0 += 16) {
                unsigned long long t[16];
#pragma unroll
                for (int j = 0; j < 16; ++j)
                    t[j] = mask[(size_t)(c * 64 + b0 + j) * NW + c2];
#pragma unroll
                for (int j = 0; j < 16; ++j)
                    sup |= ((w >> (b0 + j)) & 1ull) ? t[j] : 0ull;
            }
            kw[c2] &= ~sup;
        }
        __syncthreads();
    }
    for (int r = kept + l; r < POSN; r += 64) {
        out2[r * 4 + 0] = 0.f; out2[r * 4 + 1] = 0.f;
        out2[r * 4 + 2] = 0.f; out2[r * 4 + 3] = 0.f;
        out3[r] = 0.f;
    }
}

// ---------------------------------------------------------------------------
// gather proposals/cls at valid_idx
// ---------------------------------------------------------------------------
__global__ void k_gather(const int* __restrict__ vidx, const float* __restrict__ props,
                         const float* __restrict__ cls2, float* __restrict__ out0,
                         float* __restrict__ out1, int nv) {
    int i = blockIdx.x * 256 + threadIdx.x;
    if (i >= nv) return;
    int v = vidx[i];
    ((float4*)out0)[i] = ((const float4*)props)[v];
    ((float2*)out1)[i] = ((const float2*)cls2)[v];
}

// ---------------------------------------------------------------------------
extern "C" void kernel_launch(void* const* d_in, const int* in_sizes, int n_in,
                              void* d_out, int out_size, void* d_ws, size_t ws_size,
                              hipStream_t stream) {
    const float* x       = (const float*)d_in[0];
    const float* w_rpn   = (const float*)d_in[1];
    const float* b_rpn   = (const float*)d_in[2];
    const float* w_cls   = (const float*)d_in[3];
    const float* b_cls   = (const float*)d_in[4];
    const float* w_reg   = (const float*)d_in[5];
    const float* b_reg   = (const float*)d_in[6];
    const float* anchors = (const float*)d_in[7];
    const int*   vidx    = (const int*)d_in[8];
    const int nv = in_sizes[8];

    char* ws = (char*)d_ws;
    float* accum            = (float*)(ws + 0);
    float* props            = (float*)(ws + 1990656);
    float* boxes            = (float*)(ws + 3317760);
    float* cls2             = (float*)(ws + 4644864);
    float* dval             = (float*)(ws + 5308416);
    unsigned int* hist      = (unsigned int*)(ws + 5640192);
    unsigned int* ctrl      = (unsigned int*)(ws + 5902336);
    unsigned long long* cand = (unsigned long long*)(ws + 5902400);
    float* topBoxes         = (float*)(ws + 5967936);
    float* topProbs         = (float*)(ws + 6063936);
    unsigned long long* mask = (unsigned long long*)(ws + 6087936);  // 4.512 MB
    _Float16* xt_h          = (_Float16*)(ws + 10599936);  // 18.87 MB
    _Float16* xt_l          = (_Float16*)(ws + 29474304);  // 18.87 MB
    _Float16* wt2           = (_Float16*)(ws + 48348672);  // 18.87 MB fragment-ordered
    float* hp               = (float*)(ws + 67223040);     // 75.5 MB (4 K-splits; ends ~143 MB)
    // partial ranks (8 x 8192 u32 = 256 KB) aliased onto xt_h's region:
    // xt_h is dead after k_conv, and k_rankp runs strictly after it.
    unsigned int* rankp     = (unsigned int*)(ws + 10599936);

    float* out0 = (float*)d_out;
    float* out1 = out0 + (size_t)nv * 4;
    float* out2 = out1 + (size_t)nv * 2;
    float* out3 = out2 + (size_t)POSN * 4;

    k_init<<<(65536 + 16 + 255) / 256, 256, 0, stream>>>(hist, ctrl);
    k_xtr<<<dim3(144, 16), 256, 0, stream>>>(x, xt_h, xt_l);
    k_wtr<<<dim3(4, 32, 4), 256, 0, stream>>>(w_rpn, wt2);
    k_conv<<<1536, 512, 0, stream>>>(xt_h, xt_l, wt2, hp);
    k_post<<<384, 256, 0, stream>>>(hp, b_rpn, w_cls, w_reg, b_cls, b_reg, accum);
    k_decode<<<(NA + 255) / 256, 256, 0, stream>>>(accum, anchors, props, boxes, cls2, dval, hist);
    k_thresh<<<1, 1024, 0, stream>>>(hist, ctrl);
    k_compact<<<(NA + 255) / 256, 256, 0, stream>>>(dval, ctrl, cand);
    k_rankp<<<32 * RQ, 256, 0, stream>>>(cand, ctrl, rankp);
    k_ranks<<<32, 256, 0, stream>>>(cand, ctrl, rankp, boxes, dval, topBoxes, topProbs);
    k_mask<<<dim3(24, NW), 256, 0, stream>>>(topBoxes, mask);
    k_scan<<<1, 64, 0, stream>>>(mask, topBoxes, topProbs, out2, out3);
    k_gather<<<(nv + 255) / 256, 256, 0, stream>>>(vidx, props, cls2, out0, out1, nv);
}

// Round 10
// 592.427 us; speedup vs baseline: 1.2217x; 1.0800x over previous
//
#include <hip/hip_runtime.h>

#define H 96
#define W 96
#define CIN 1024
#define NPIX 9216          // 96*96
#define NCH 54             // 18 cls + 36 reg channels
#define NA 82944           // 9216*9 anchors
#define TOPN 6000
#define NW 94              // ceil(6000/64)
#define POSN 300
#define CAND_CAP 8192
#define RQ 8               // k_rank j-range split factor
#define RCHUNK 1024        // CAND_CAP / RQ

typedef _Float16 half8_t __attribute__((ext_vector_type(8)));
typedef float f32x4 __attribute__((ext_vector_type(4)));

#define CIP 40             // padded ci stride in halves (80 B: 16B-aligned, 2-way banks = free)
#define XS_PLANE 11760     // 3*98*40 halves
#define HP_SPLIT 4718592   // 4*9216*128 floats per K-split buffer

// ---------------------------------------------------------------------------
// init: hist/ctrl <- 0
// ---------------------------------------------------------------------------
__global__ void k_init(unsigned int* __restrict__ hist, unsigned int* __restrict__ ctrl) {
    int t = blockIdx.x * 256 + threadIdx.x;
    if (t < 65536) hist[t] = 0u;
    else if (t < 65536 + 16) ctrl[t - 65536] = 0u;
}

// ---------------------------------------------------------------------------
// x transpose + fp16 split: x[ci][px] fp32 -> xt_h[px][ci], xt_l[px][ci]
// half8 (16B/lane) vectorized stores.
// ---------------------------------------------------------------------------
__global__ __launch_bounds__(256) void k_xtr(const float* __restrict__ x,
                                             _Float16* __restrict__ xh,
                                             _Float16* __restrict__ xl) {
    __shared__ float t[64 * 65];
    const int tid = threadIdx.x;
    const int px0 = blockIdx.x * 64, ci0 = blockIdx.y * 64;
    for (int i = tid; i < 4096; i += 256) {
        int ci = i >> 6, px = i & 63;
        t[ci * 65 + px] = x[(size_t)(ci0 + ci) * NPIX + px0 + px];
    }
    __syncthreads();
    for (int i = tid; i < 512; i += 256) {     // 64 px x 8 ci-octets
        int px = i >> 3, q = i & 7;
        _Float16 h8[8], l8[8];
#pragma unroll
        for (int j = 0; j < 8; ++j) {
            float v = t[(q * 8 + j) * 65 + px];
            _Float16 h = (_Float16)v;
            h8[j] = h;
            l8[j] = (_Float16)((v - (float)h) * 2048.f);
        }
        size_t o = (size_t)(px0 + px) * 1024 + ci0 + q * 8;
        *(half8_t*)(xh + o) = *(half8_t*)h8;
        *(half8_t*)(xl + o) = *(half8_t*)l8;
    }
}

// ---------------------------------------------------------------------------
// weight transform to MFMA-fragment order + fp16 split (coalesced).
// R4: g-loop split onto blockIdx.z -> 512 blocks (was 128; half the GPU idle).
// ---------------------------------------------------------------------------
__global__ __launch_bounds__(256) void k_wtr(const float* __restrict__ wr,
                                             _Float16* __restrict__ wt2) {
    __shared__ float tile[32 * 292];
    const int cb = blockIdx.x, cc = blockIdx.y, g = blockIdx.z;
    const int tid = threadIdx.x;
    for (int i = tid; i < 32 * 288; i += 256) {
        int row = i / 288, col = i - row * 288;
        tile[row * 292 + col] = wr[(size_t)(cb * 128 + g * 32 + row) * 9216 + cc * 288 + col];
    }
    __syncthreads();
#pragma unroll
    for (int k = 0; k < 9; ++k) {
        int G = k * 256 + tid;           // < 2304
        int tap = G >> 8, r = G & 255;
        int pl = r >> 7, ntl = (r >> 6) & 1, l = r & 63;
        int co_loc = ntl * 16 + (l & 15);
        int ci_b = (l >> 4) * 8;
        _Float16 o8[8];
#pragma unroll
        for (int j = 0; j < 8; ++j) {
            float v = tile[co_loc * 292 + (ci_b + j) * 9 + tap];
            _Float16 h = (_Float16)v;
            o8[j] = pl ? (_Float16)((v - (float)h) * 2048.f) : h;
        }
        _Float16* dst = wt2 + ((size_t)((tap * 4 + cb) * 32 + cc)) * 8192 +
                        (size_t)(pl * 8 + (g * 2 + ntl)) * 512 + l * 8;
        *(half8_t*)dst = *(half8_t*)o8;
    }
}

// ---------------------------------------------------------------------------
// MFMA implicit-GEMM conv3x3(1024->512), K-split by 4.  [R5-proven, 240us]
// fp16 2-plane split: h = Ah*Bh + (Ah*Bl' + Al'*Bh)/2048.
// Block = 1 row (96 px) x 128 co, 4 waves; wave = 3 m-tiles x 4 n-tiles.
// B direct from global (fragment-ordered wt2), prefetched one tap ahead;
// x register-prefetched one chunk ahead. 2 blocks/CU.
// Grid 1536 = exactly 3 residency rounds at 2 blocks/CU.
//
// CONV STRUCTURE LEDGER (unified 512 regs/lane/SIMD, gfx950) — do not retry:
//   R5 4-wave 256thr: 128 VGPR + 96 AGPR = 224/wave, 2 waves/SIMD -> 240us
//   R2 +32 VGPR prefetch: spill (FETCH +315 MB) -> 417us
//   R6 8-wave (512,4): launch_bounds 2nd arg = MIN BLOCKS/CU (CUDA
//      semantics) -> VGPR cap 64 -> spill -> 417us (but 112/wave DID
//      fit 4 waves/SIMD)
//   R7 8-wave (512,2): 80+48=128/wave -> only 1 block/CU (threshold<128)
//   R8 8-wave no-prefetch: 84+48=132/wave -> 1 block/CU, 286us.
//   8-wave needs <=~76 VGPR; address-math floor is ~84. ABANDONED.
//
// Y-BAND XCD SWIZZLE: with round-robin bid%8 -> XCD dispatch, XCD k gets
// rows [12k,12k+12) for ALL (cb,ks).
// Epilogue LDS tile padded 96x132 f32 (breaks 4-way store bank conflict).
// ---------------------------------------------------------------------------
__global__ __launch_bounds__(256, 2) void k_conv(
    const _Float16* __restrict__ xth, const _Float16* __restrict__ xtl,
    const _Float16* __restrict__ wt2, float* __restrict__ hp) {
    __shared__ __align__(16) char smem[50688];   // xs 47040 B; epilogue 96x132 f32
    _Float16* xs = (_Float16*)smem;

    const int tid = threadIdx.x;
    const int bid = blockIdx.x;
    const int xcd = bid & 7;
    const int i8  = bid >> 3;          // 0..191
    const int y   = xcd * 12 + (i8 % 12);
    const int cbks = i8 / 12;          // 0..15
    const int cb  = cbks & 3;          // co block of 128
    const int ks  = cbks >> 2;         // K-split quarter (0..3)
    const int l  = tid & 63;
    const int wv = tid >> 6;          // 0..3
    const int mg = wv & 1;            // m-group
    const int ng = wv >> 1;           // n-group
    const int lm = l & 15;
    const int lk = l >> 4;            // 0..3

    f32x4 acc_h[3][4];
    f32x4 acc_x[3][4];
#pragma unroll
    for (int m2 = 0; m2 < 3; ++m2)
#pragma unroll
        for (int nt = 0; nt < 4; ++nt) {
            acc_h[m2][nt] = (f32x4){0.f, 0.f, 0.f, 0.f};
            acc_x[m2][nt] = (f32x4){0.f, 0.f, 0.f, 0.f};
        }

    // zero px pad columns (pxp = 0 and 97), both planes, 3 rows
    for (int i = tid; i < 480; i += 256) {
        int pl = i / 240, j = i - pl * 240;
        int r = j / 80, j2 = j - r * 80;
        int side = j2 / 40, c = j2 - side * 40;
        xs[pl * XS_PLANE + (r * 98 + side * 97) * CIP + c] = (_Float16)0.f;
    }

    auto ldx = [&](float4* xr, int cc_) {
#pragma unroll
        for (int k = 0; k < 9; ++k) {
            int item = k * 256 + tid;
            int pl = (item >= 1152) ? 1 : 0;
            int j = item - pl * 1152;
            int r = j / 384, j2 = j - r * 384;
            int px = j2 >> 2, q = j2 & 3;
            int yy = y + r - 1;
            float4 v = {0.f, 0.f, 0.f, 0.f};
            if (yy >= 0 && yy < H)
                v = *(const float4*)((pl ? xtl : xth) + (size_t)(yy * 96 + px) * 1024 + cc_ * 32 + q * 8);
            xr[k] = v;
        }
    };
    auto stx = [&](const float4* xr) {
#pragma unroll
        for (int k = 0; k < 9; ++k) {
            int item = k * 256 + tid;
            int pl = (item >= 1152) ? 1 : 0;
            int j = item - pl * 1152;
            int r = j / 384, j2 = j - r * 384;
            int px = j2 >> 2, q = j2 & 3;
            *(float4*)(xs + pl * XS_PLANE + (r * 98 + px + 1) * CIP + q * 8) = xr[k];
        }
    };
    auto ldb = [&](half8_t* bh, half8_t* bl, int cc_, int tap_) {
        const _Float16* base = wt2 + ((size_t)((tap_ * 4 + cb) * 32 + cc_) * 16) * 512 + (size_t)l * 8;
#pragma unroll
        for (int nt = 0; nt < 4; ++nt) {
            bh[nt] = *(const half8_t*)(base + (size_t)(ng * 4 + nt) * 512);
            bl[nt] = *(const half8_t*)(base + (size_t)(8 + ng * 4 + nt) * 512);
        }
    };

    const int cc0 = ks * 8;
    const int ccE = cc0 + 8;
    float4 xr[9];
    ldx(xr, cc0);
    half8_t bnh[4], bnl[4];
    ldb(bnh, bnl, cc0, 0);

    for (int cc = cc0; cc < ccE; ++cc) {
        __syncthreads();           // previous chunk's xs reads complete
        stx(xr);
        __syncthreads();           // xs visible
        const int ccn = (cc + 1 < ccE) ? cc + 1 : cc;
        ldx(xr, ccn);              // prefetch next chunk's x (in flight during taps)

#pragma unroll
        for (int tap = 0; tap < 9; ++tap) {
            half8_t bh[4], bl[4];
#pragma unroll
            for (int nt = 0; nt < 4; ++nt) { bh[nt] = bnh[nt]; bl[nt] = bnl[nt]; }
            const int ntap = (tap == 8) ? 0 : tap + 1;
            const int ncc  = (tap == 8) ? ccn : cc;
            ldb(bnh, bnl, ncc, ntap);   // prefetch next tap's B

            const int ky = tap / 3, kx = tap - 3 * (tap / 3);
            half8_t ah[3], al[3];
#pragma unroll
            for (int m2 = 0; m2 < 3; ++m2) {
                const int pxp = (mg * 3 + m2) * 16 + lm + kx;
                ah[m2] = *(const half8_t*)(xs + (ky * 98 + pxp) * CIP + lk * 8);
                al[m2] = *(const half8_t*)(xs + XS_PLANE + (ky * 98 + pxp) * CIP + lk * 8);
            }
#pragma unroll
            for (int m2 = 0; m2 < 3; ++m2)
#pragma unroll
                for (int nt = 0; nt < 4; ++nt)
                    acc_h[m2][nt] = __builtin_amdgcn_mfma_f32_16x16x32_f16(ah[m2], bh[nt], acc_h[m2][nt], 0, 0, 0);
#pragma unroll
            for (int m2 = 0; m2 < 3; ++m2)
#pragma unroll
                for (int nt = 0; nt < 4; ++nt)
                    acc_x[m2][nt] = __builtin_amdgcn_mfma_f32_16x16x32_f16(ah[m2], bl[nt], acc_x[m2][nt], 0, 0, 0);
#pragma unroll
            for (int m2 = 0; m2 < 3; ++m2)
#pragma unroll
                for (int nt = 0; nt < 4; ++nt)
                    acc_x[m2][nt] = __builtin_amdgcn_mfma_f32_16x16x32_f16(al[m2], bh[nt], acc_x[m2][nt], 0, 0, 0);
        }
    }

    // ---- epilogue: combine planes, bounce through LDS, coalesced store ----
    __syncthreads();
    float* cs = (float*)smem;
#pragma unroll
    for (int m2 = 0; m2 < 3; ++m2)
#pragma unroll
        for (int nt = 0; nt < 4; ++nt) {
            int co = (ng * 4 + nt) * 16 + lm;
#pragma unroll
            for (int r = 0; r < 4; ++r) {
                int px = (mg * 3 + m2) * 16 + lk * 4 + r;
                cs[px * 132 + co] = acc_h[m2][nt][r] + acc_x[m2][nt][r] * (1.f / 2048.f);
            }
        }
    __syncthreads();
    float4* dst = (float4*)(hp + ((size_t)(ks * 4 + cb) * NPIX + y * 96) * 128);
    for (int i = tid; i < 3072; i += 256) {
        int px = i >> 5, c4 = i & 31;
        dst[i] = *(const float4*)(cs + px * 132 + c4 * 4);
    }
}

// ---------------------------------------------------------------------------
// post: h = relu(hp0+hp1+hp2+hp3+b_rpn) staged in LDS; 1x1 convs (54 ch).
// ---------------------------------------------------------------------------
__global__ __launch_bounds__(256, 2) void k_post(const float* __restrict__ hp,
                                                 const float* __restrict__ br,
                                                 const float* __restrict__ wcl,
                                                 const float* __restrict__ wrg,
                                                 const float* __restrict__ bcl,
                                                 const float* __restrict__ brg,
                                                 float* __restrict__ accum) {
    __shared__ float hsm[24 * 520];
    __shared__ float wcs[54 * 130];
    const int tid = threadIdx.x;
    const int gp0 = blockIdx.x * 24;

    for (int i = tid; i < 24 * 512; i += 256) {
        int px = i >> 9, ci = i & 511;
        int cbk = ci >> 7, co = ci & 127;
        size_t off = ((size_t)cbk * NPIX + gp0 + px) * 128 + co;
        float v = hp[off] + hp[off + HP_SPLIT] + hp[off + 2 * (size_t)HP_SPLIT] +
                  hp[off + 3 * (size_t)HP_SPLIT] + br[ci];
        hsm[px * 520 + ci] = fmaxf(v, 0.f);
    }

    const int px  = tid >> 3;
    const int chb = tid & 7;
    float part[7];
#pragma unroll
    for (int k = 0; k < 7; ++k) part[k] = 0.f;

    for (int chunk = 0; chunk < 4; ++chunk) {
        __syncthreads();
        for (int i = tid; i < 54 * 128; i += 256) {
            int ch = i >> 7, j = i & 127;
            wcs[ch * 130 + j] = (ch < 18) ? wcl[ch * 512 + chunk * 128 + j]
                                          : wrg[(ch - 18) * 512 + chunk * 128 + j];
        }
        __syncthreads();
        if (px < 24) {
            const float4* hv = (const float4*)(hsm + px * 520 + chunk * 128);
#pragma unroll 4
            for (int q = 0; q < 32; ++q) {
                float4 hq = hv[q];
#pragma unroll
                for (int k = 0; k < 7; ++k) {
                    int ch = chb * 7 + k;
                    if (ch < 54) {
                        float4 wq = *(const float4*)(wcs + ch * 130 + q * 4);
                        part[k] += hq.x * wq.x + hq.y * wq.y + hq.z * wq.z + hq.w * wq.w;
                    }
                }
            }
        }
    }
    if (px < 24) {
#pragma unroll
        for (int k = 0; k < 7; ++k) {
            int ch = chb * 7 + k;
            if (ch < 54) {
                float b = (ch < 18) ? bcl[ch] : brg[ch - 18];
                accum[(size_t)(gp0 + px) * NCH + ch] = part[k] + b;
            }
        }
    }
}

// ---------------------------------------------------------------------------
// decode: anchors + reg -> proposals/clipped boxes; cls -> d = c1-c0; histogram
// ---------------------------------------------------------------------------
__device__ __forceinline__ unsigned int key_of(float d) {
    unsigned int u = __float_as_uint(d);
    unsigned int k = (u & 0x80000000u) ? ~u : (u | 0x80000000u);  // asc in d
    return ~k;                                                     // asc key = desc d
}

__global__ void k_decode(const float* __restrict__ accum, const float* __restrict__ anchors,
                         float* __restrict__ props, float* __restrict__ boxes,
                         float* __restrict__ cls2, float* __restrict__ dval,
                         unsigned int* __restrict__ hist) {
    int idx = blockIdx.x * 256 + threadIdx.x;
    if (idx >= NA) return;
    int p = idx / 9, a = idx - p * 9;
    const float* ac = accum + p * NCH;
    float c0 = ac[2 * a], c1 = ac[2 * a + 1];
    float r0 = ac[18 + 4 * a + 0], r1 = ac[18 + 4 * a + 1];
    float r2 = ac[18 + 4 * a + 2], r3 = ac[18 + 4 * a + 3];
    const float* A = anchors + (size_t)idx * 4;
    float aw = A[2] - A[0] + 1.f, ah = A[3] - A[1] + 1.f;
    float ax = A[0] + 0.5f * (aw - 1.f), ay = A[1] + 0.5f * (ah - 1.f);
    float px = ax + aw * r0, py = ay + ah * r1;
    float pw = aw * expf(r2), ph = ah * expf(r3);
    float p0 = px - 0.5f * (pw - 1.f), p1 = py - 0.5f * (ph - 1.f);
    float p2 = px + 0.5f * (pw - 1.f), p3 = py + 0.5f * (ph - 1.f);
    props[idx * 4 + 0] = p0; props[idx * 4 + 1] = p1;
    props[idx * 4 + 2] = p2; props[idx * 4 + 3] = p3;
    boxes[idx * 4 + 0] = fminf(fmaxf(p0, 0.f), (float)(1536 - 1));
    boxes[idx * 4 + 1] = fminf(fmaxf(p1, 0.f), (float)(1536 - 1));
    boxes[idx * 4 + 2] = fminf(fmaxf(p2, 0.f), (float)(1536 - 1));
    boxes[idx * 4 + 3] = fminf(fmaxf(p3, 0.f), (float)(1536 - 1));
    cls2[idx * 2 + 0] = c0; cls2[idx * 2 + 1] = c1;
    float d = c1 - c0;
    dval[idx] = d;
    atomicAdd(&hist[key_of(d) >> 16], 1u);
}

// ---------------------------------------------------------------------------
// threshold: find histogram bin T containing rank-6000.
// R4: wave-reduce before LDS atomic (old: 64-way same-address LDS-atomic
// serialization, ~25us on one CU). shfl tree + 1 atomic per wave-iteration.
// ---------------------------------------------------------------------------
__global__ __launch_bounds__(1024) void k_thresh(const unsigned int* __restrict__ hist,
                                                 unsigned int* __restrict__ ctrl) {
    __shared__ unsigned int s[256];
    __shared__ unsigned int ss[256];
    __shared__ unsigned int chunkIdx, baseCount;
    const int tid = threadIdx.x;
    if (tid < 256) s[tid] = 0u;
    __syncthreads();
    for (int i = tid; i < 65536; i += 1024) {
        unsigned int v = hist[i];
#pragma unroll
        for (int d = 32; d > 0; d >>= 1) v += __shfl_down(v, d);
        if ((tid & 63) == 0) atomicAdd(&s[i >> 8], v);
    }
    __syncthreads();
    if (tid == 0) {
        unsigned int cum = 0; int c = 0;
        for (; c < 256; ++c) { if (cum + s[c] >= TOPN) break; cum += s[c]; }
        chunkIdx = (unsigned int)c; baseCount = cum;
    }
    __syncthreads();
    if (tid < 256) ss[tid] = hist[chunkIdx * 256 + tid];
    __syncthreads();
    if (tid == 0) {
        unsigned int cum = baseCount; int b = 0;
        for (; b < 256; ++b) { cum += ss[b]; if (cum >= TOPN) break; }
        ctrl[1] = chunkIdx * 256 + (unsigned int)b;  // T
        ctrl[2] = cum;
    }
}

// ---------------------------------------------------------------------------
// compact candidates (bin <= T): per-block LDS aggregation, 1 global atomic.
// ---------------------------------------------------------------------------
__global__ __launch_bounds__(256) void k_compact(const float* __restrict__ dval,
                                                 unsigned int* __restrict__ ctrl,
                                                 unsigned long long* __restrict__ cand) {
    __shared__ unsigned int cnt, base;
    const int tid = threadIdx.x;
    const int idx = blockIdx.x * 256 + tid;
    if (tid == 0) cnt = 0u;
    __syncthreads();
    unsigned int k2 = 0; bool pass = false; unsigned int pos = 0;
    if (idx < NA) {
        k2 = key_of(dval[idx]);
        pass = (k2 >> 16) <= ctrl[1];
        if (pass) pos = atomicAdd(&cnt, 1u);
    }
    __syncthreads();
    if (tid == 0) base = atomicAdd(&ctrl[0], cnt);
    __syncthreads();
    if (pass) {
        unsigned int p = base + pos;
        if (p < CAND_CAP) cand[p] = ((unsigned long long)k2 << 32) | (unsigned int)idx;
    }
}

// ---------------------------------------------------------------------------
// rank-by-count, j-range split 8 ways: block (ci,jq) ranks candidates
// ci*256..+256 against key slice jq*1024..+1024, WRITES partial rank to
// rankp[jq*CAND_CAP + i] (no atomics, no init).
// ---------------------------------------------------------------------------
__global__ __launch_bounds__(256) void k_rankp(const unsigned long long* __restrict__ cand,
                                               const unsigned int* __restrict__ ctrl,
                                               unsigned int* __restrict__ rankp) {
    __shared__ unsigned long long sc[RCHUNK];   // 8 KB
    const int tid = threadIdx.x;
    const int ci = blockIdx.x >> 3;            // candidate chunk 0..31
    const int jq = blockIdx.x & 7;             // j-slice 0..7
    unsigned int n = ctrl[0]; if (n > CAND_CAP) n = CAND_CAP;
    const int jb = jq * RCHUNK;
    for (int i = tid; i < RCHUNK; i += 256) {
        int j = jb + i;
        sc[i] = (j < (int)n) ? cand[j] : 0xFFFFFFFFFFFFFFFFull;  // pads never < mine
    }
    __syncthreads();
    const int i = ci * 256 + tid;
    // keep ALL lanes active through the shfl loop (inactive lanes would
    // poison __shfl reads for their wave-mates)
    const unsigned long long mine = (i < (int)n) ? cand[i] : 0xFFFFFFFFFFFFFFFFull;
    const int l = tid & 63;
    int nq = (int)n - jb; if (nq < 0) nq = 0; if (nq > RCHUNK) nq = RCHUNK;
    const int nr = (nq + 63) & ~63;
    int rank = 0;
    for (int j0 = 0; j0 < nr; j0 += 64) {
        unsigned long long kj = sc[j0 + l];
#pragma unroll
        for (int b = 0; b < 64; ++b) {
            unsigned long long kb = __shfl(kj, b);
            rank += (kb < mine) ? 1 : 0;
        }
    }
    if (i < (int)n) rankp[jq * CAND_CAP + i] = (unsigned int)rank;
}

// ---------------------------------------------------------------------------
// sum the 8 partial ranks, scatter boxes/probs at final rank.
// ---------------------------------------------------------------------------
__global__ __launch_bounds__(256) void k_ranks(const unsigned long long* __restrict__ cand,
                                               const unsigned int* __restrict__ ctrl,
                                               const unsigned int* __restrict__ rankp,
                                               const float* __restrict__ boxes,
                                               const float* __restrict__ dval,
                                               float* __restrict__ topBoxes,
                                               float* __restrict__ topProbs) {
    const int i = blockIdx.x * 256 + threadIdx.x;
    unsigned int n = ctrl[0]; if (n > CAND_CAP) n = CAND_CAP;
    if (i >= (int)n) return;
    unsigned int rank = 0;
#pragma unroll
    for (int q = 0; q < RQ; ++q) rank += rankp[q * CAND_CAP + i];
    if (rank < TOPN) {
        unsigned long long mine = cand[i];
        unsigned int idx = (unsigned int)mine;
        ((float4*)topBoxes)[rank] = ((const float4*)boxes)[idx];
        topProbs[rank] = 1.f / (1.f + expf(-dval[idx]));
    }
}

// ---------------------------------------------------------------------------
// NMS suppression bitmask, triangular grid.
// R9: TRANSPOSED mask layout maskT[ci][c2][b] (ci=i>>6, b=i&63),
// 94*94*64 u64 = 4.523 MB (slot enlarged vs old 4.512 MB — see launcher).
// k_scan's c2-sweep then reads one CONTIGUOUS (NW-c)*512 B stream per
// iteration instead of 8B words 752 B apart (8x cache-line over-fetch on
// a single-wave latency-bound kernel whose reads mostly miss local L2 —
// mask was written by all 8 XCDs).
// maskT[93][*][48..63] is never written; k_scan only consumes those lanes
// under w-bits that are 0 by construction (kw[93] init masks b>=48).
// R4: c-block's 64 boxes staged in LDS; whole-block diagonal early-out.
// ---------------------------------------------------------------------------
__global__ __launch_bounds__(256) void k_mask(const float* __restrict__ topBoxes,
                                              unsigned long long* __restrict__ mask) {
    const int c = blockIdx.y;
    if (c < blockIdx.x * 4) return;            // whole block below diagonal
    __shared__ float4 bsh[64];
    const int tid = threadIdx.x;
    const int i = blockIdx.x * 256 + tid;
    if (tid < 64) {
        int j = c * 64 + tid;
        float4 bv = {0.f, 0.f, 0.f, 0.f};
        if (j < TOPN) bv = ((const float4*)topBoxes)[j];
        bsh[tid] = bv;
    }
    __syncthreads();
    if (i >= TOPN || c < (i >> 6)) return;
    float4 bi = ((const float4*)topBoxes)[i];
    float ai = (bi.z - bi.x + 1.f) * (bi.w - bi.y + 1.f);
    unsigned long long m = 0;
    int j0 = c * 64;
    for (int b = 0; b < 64; ++b) {
        int j = j0 + b;
        if (j >= TOPN || j <= i) continue;
        float4 bj = bsh[b];
        float aj = (bj.z - bj.x + 1.f) * (bj.w - bj.y + 1.f);
        float iw = fmaxf(fminf(bi.z, bj.z) - fmaxf(bi.x, bj.x) + 1.f, 0.f);
        float ih = fmaxf(fminf(bi.w, bj.w) - fmaxf(bi.y, bj.y) + 1.f, 0.f);
        float inter = iw * ih;
        float iou = inter / (ai + aj - inter);
        if (iou > 0.7f) m |= (1ull << b);
    }
    // transposed store: maskT[i>>6][c][i&63]
    mask[((size_t)(i >> 6) * NW + c) * 64 + (i & 63)] = m;
}

// ---------------------------------------------------------------------------
// greedy scan, single wave, batched unconditional loads, early exit at 300.
// [R3-proven control flow; R9 only remaps mask indices to the transposed
// layout — diagonal word and c2-sweep are now contiguous streams.]
// ---------------------------------------------------------------------------
__global__ __launch_bounds__(64) void k_scan(const unsigned long long* __restrict__ mask,
                                             const float* __restrict__ topBoxes,
                                             const float* __restrict__ topProbs,
                                             float* __restrict__ out2, float* __restrict__ out3) {
    __shared__ unsigned long long kw[NW];
    int l = threadIdx.x;
    for (int i = l; i < NW; i += 64)
        kw[i] = (i == NW - 1) ? 0x0000FFFFFFFFFFFFull : ~0ull;  // 6000 = 93*64+48
    __syncthreads();
    int kept = 0;
    for (int c = 0; c < NW && kept < POSN; ++c) {
        unsigned long long w = kw[c];
        unsigned long long m = mask[((size_t)c * NW + c) * 64 + l];   // maskT[c][c][l]
        for (int b = 0; b < 64; ++b) {
            if ((w >> b) & 1ull) {
                unsigned long long mb = __shfl(m, b);
                w &= ~mb;
            }
        }
        if ((w >> l) & 1ull) {
            int r = kept + __popcll(w & ((1ull << l) - 1ull));
            if (r < POSN) {
                int j = c * 64 + l;
                out2[r * 4 + 0] = topBoxes[j * 4 + 0];
                out2[r * 4 + 1] = topBoxes[j * 4 + 1];
                out2[r * 4 + 2] = topBoxes[j * 4 + 2];
                out2[r * 4 + 3] = topBoxes[j * 4 + 3];
                out3[r] = topProbs[j];
            }
        }
        kept += __popcll(w);
        if (kept >= POSN) break;
        for (int c2 = c + 1 + l; c2 < NW; c2 += 64) {
            const unsigned long long* mrow = mask + ((size_t)c * NW + c2) * 64;  // maskT[c][c2][*]
            unsigned long long sup = 0;
#pragma unroll
            for (int b0 = 0; b0 < 64; b0 += 16) {
                unsigned long long t[16];
#pragma unroll
                for (int j = 0; j < 16; ++j)
                    t[j] = mrow[b0 + j];
#pragma unroll
                for (int j = 0; j < 16; ++j)
                    sup |= ((w >> (b0 + j)) & 1ull) ? t[j] : 0ull;
            }
            kw[c2] &= ~sup;
        }
        __syncthreads();
    }
    for (int r = kept + l; r < POSN; r += 64) {
        out2[r * 4 + 0] = 0.f; out2[r * 4 + 1] = 0.f;
        out2[r * 4 + 2] = 0.f; out2[r * 4 + 3] = 0.f;
        out3[r] = 0.f;
    }
}

// ---------------------------------------------------------------------------
// gather proposals/cls at valid_idx
// ---------------------------------------------------------------------------
__global__ void k_gather(const int* __restrict__ vidx, const float* __restrict__ props,
                         const float* __restrict__ cls2, float* __restrict__ out0,
                         float* __restrict__ out1, int nv) {
    int i = blockIdx.x * 256 + threadIdx.x;
    if (i >= nv) return;
    int v = vidx[i];
    ((float4*)out0)[i] = ((const float4*)props)[v];
    ((float2*)out1)[i] = ((const float2*)cls2)[v];
}

// ---------------------------------------------------------------------------
extern "C" void kernel_launch(void* const* d_in, const int* in_sizes, int n_in,
                              void* d_out, int out_size, void* d_ws, size_t ws_size,
                              hipStream_t stream) {
    const float* x       = (const float*)d_in[0];
    const float* w_rpn   = (const float*)d_in[1];
    const float* b_rpn   = (const float*)d_in[2];
    const float* w_cls   = (const float*)d_in[3];
    const float* b_cls   = (const float*)d_in[4];
    const float* w_reg   = (const float*)d_in[5];
    const float* b_reg   = (const float*)d_in[6];
    const float* anchors = (const float*)d_in[7];
    const int*   vidx    = (const int*)d_in[8];
    const int nv = in_sizes[8];

    char* ws = (char*)d_ws;
    float* accum            = (float*)(ws + 0);
    float* props            = (float*)(ws + 1990656);
    float* boxes            = (float*)(ws + 3317760);
    float* cls2             = (float*)(ws + 4644864);
    float* dval             = (float*)(ws + 5308416);
    unsigned int* hist      = (unsigned int*)(ws + 5640192);
    unsigned int* ctrl      = (unsigned int*)(ws + 5902336);
    unsigned long long* cand = (unsigned long long*)(ws + 5902400);
    float* topBoxes         = (float*)(ws + 5967936);
    float* topProbs         = (float*)(ws + 6063936);
    unsigned long long* mask = (unsigned long long*)(ws + 6087936);  // transposed maskT: 94*94*512 = 4.523 MB (ends 10610944)
    _Float16* xt_h          = (_Float16*)(ws + 10599936);  // 18.87 MB (first 11 KB overlapped by maskT tail — xt_h dead before k_mask)
    _Float16* xt_l          = (_Float16*)(ws + 29474304);  // 18.87 MB
    _Float16* wt2           = (_Float16*)(ws + 48348672);  // 18.87 MB fragment-ordered
    float* hp               = (float*)(ws + 67223040);     // 75.5 MB (4 K-splits; ends ~143 MB)
    // partial ranks (8 x 8192 u32 = 256 KB) in xt_h's dead region, placed
    // 16 KB past its start so maskT's 11 KB tail (ends at 10610944) can
    // never alias rankp even though both outlive k_rankp/k_ranks.
    unsigned int* rankp     = (unsigned int*)(ws + 10616320);

    float* out0 = (float*)d_out;
    float* out1 = out0 + (size_t)nv * 4;
    float* out2 = out1 + (size_t)nv * 2;
    float* out3 = out2 + (size_t)POSN * 4;

    k_init<<<(65536 + 16 + 255) / 256, 256, 0, stream>>>(hist, ctrl);
    k_xtr<<<dim3(144, 16), 256, 0, stream>>>(x, xt_h, xt_l);
    k_wtr<<<dim3(4, 32, 4), 256, 0, stream>>>(w_rpn, wt2);
    k_conv<<<1536, 256, 0, stream>>>(xt_h, xt_l, wt2, hp);
    k_post<<<384, 256, 0, stream>>>(hp, b_rpn, w_cls, w_reg, b_cls, b_reg, accum);
    k_decode<<<(NA + 255) / 256, 256, 0, stream>>>(accum, anchors, props, boxes, cls2, dval, hist);
    k_thresh<<<1, 1024, 0, stream>>>(hist, ctrl);
    k_compact<<<(NA + 255) / 256, 256, 0, stream>>>(dval, ctrl, cand);
    k_rankp<<<32 * RQ, 256, 0, stream>>>(cand, ctrl, rankp);
    k_ranks<<<32, 256, 0, stream>>>(cand, ctrl, rankp, boxes, dval, topBoxes, topProbs);
    k_mask<<<dim3(24, NW), 256, 0, stream>>>(topBoxes, mask);
    k_scan<<<1, 64, 0, stream>>>(mask, topBoxes, topProbs, out2, out3);
    k_gather<<<(nv + 255) / 256, 256, 0, stream>>>(vidx, props, cls2, out0, out1, nv);
}

// Round 11
// 591.303 us; speedup vs baseline: 1.2240x; 1.0019x over previous
//
#include <hip/hip_runtime.h>

#define H 96
#define W 96
#define CIN 1024
#define NPIX 9216          // 96*96
#define NCH 54             // 18 cls + 36 reg channels
#define NA 82944           // 9216*9 anchors
#define TOPN 6000
#define NW 94              // ceil(6000/64)
#define POSN 300
#define CAND_CAP 8192
#define RQ 8               // k_rank j-range split factor
#define RCHUNK 1024        // CAND_CAP / RQ

typedef _Float16 half8_t __attribute__((ext_vector_type(8)));
typedef float f32x4 __attribute__((ext_vector_type(4)));

#define CIP 40             // padded ci stride in halves (80 B: 16B-aligned, 2-way banks = free)
#define XS_PLANE 11760     // 3*98*40 halves
#define HP_SPLIT 4718592   // 4*9216*128 floats per K-split buffer

// ---------------------------------------------------------------------------
// x transpose + fp16 split: x[ci][px] fp32 -> xt_h[px][ci], xt_l[px][ci]
// half8 (16B/lane) vectorized stores.
// R11: k_init folded in — first 257 flat blocks zero hist/ctrl (runs 4
// kernels before k_postdec's atomics; stream-ordered, so safe).
// ---------------------------------------------------------------------------
__global__ __launch_bounds__(256) void k_xtr(const float* __restrict__ x,
                                             _Float16* __restrict__ xh,
                                             _Float16* __restrict__ xl,
                                             unsigned int* __restrict__ hist,
                                             unsigned int* __restrict__ ctrl) {
    __shared__ float t[64 * 65];
    const int tid = threadIdx.x;
    const int fb = blockIdx.y * 144 + blockIdx.x;
    if (fb < 257) {
        int g = fb * 256 + tid;
        if (g < 65536) hist[g] = 0u;
        else if (g < 65536 + 16) ctrl[g - 65536] = 0u;
    }
    const int px0 = blockIdx.x * 64, ci0 = blockIdx.y * 64;
    for (int i = tid; i < 4096; i += 256) {
        int ci = i >> 6, px = i & 63;
        t[ci * 65 + px] = x[(size_t)(ci0 + ci) * NPIX + px0 + px];
    }
    __syncthreads();
    for (int i = tid; i < 512; i += 256) {     // 64 px x 8 ci-octets
        int px = i >> 3, q = i & 7;
        _Float16 h8[8], l8[8];
#pragma unroll
        for (int j = 0; j < 8; ++j) {
            float v = t[(q * 8 + j) * 65 + px];
            _Float16 h = (_Float16)v;
            h8[j] = h;
            l8[j] = (_Float16)((v - (float)h) * 2048.f);
        }
        size_t o = (size_t)(px0 + px) * 1024 + ci0 + q * 8;
        *(half8_t*)(xh + o) = *(half8_t*)h8;
        *(half8_t*)(xl + o) = *(half8_t*)l8;
    }
}

// ---------------------------------------------------------------------------
// weight transform to MFMA-fragment order + fp16 split (coalesced).
// R4: g-loop split onto blockIdx.z -> 512 blocks (was 128; half the GPU idle).
// ---------------------------------------------------------------------------
__global__ __launch_bounds__(256) void k_wtr(const float* __restrict__ wr,
                                             _Float16* __restrict__ wt2) {
    __shared__ float tile[32 * 292];
    const int cb = blockIdx.x, cc = blockIdx.y, g = blockIdx.z;
    const int tid = threadIdx.x;
    for (int i = tid; i < 32 * 288; i += 256) {
        int row = i / 288, col = i - row * 288;
        tile[row * 292 + col] = wr[(size_t)(cb * 128 + g * 32 + row) * 9216 + cc * 288 + col];
    }
    __syncthreads();
#pragma unroll
    for (int k = 0; k < 9; ++k) {
        int G = k * 256 + tid;           // < 2304
        int tap = G >> 8, r = G & 255;
        int pl = r >> 7, ntl = (r >> 6) & 1, l = r & 63;
        int co_loc = ntl * 16 + (l & 15);
        int ci_b = (l >> 4) * 8;
        _Float16 o8[8];
#pragma unroll
        for (int j = 0; j < 8; ++j) {
            float v = tile[co_loc * 292 + (ci_b + j) * 9 + tap];
            _Float16 h = (_Float16)v;
            o8[j] = pl ? (_Float16)((v - (float)h) * 2048.f) : h;
        }
        _Float16* dst = wt2 + ((size_t)((tap * 4 + cb) * 32 + cc)) * 8192 +
                        (size_t)(pl * 8 + (g * 2 + ntl)) * 512 + l * 8;
        *(half8_t*)dst = *(half8_t*)o8;
    }
}

// ---------------------------------------------------------------------------
// MFMA implicit-GEMM conv3x3(1024->512), K-split by 4.  [R5-proven, 240us]
// fp16 2-plane split: h = Ah*Bh + (Ah*Bl' + Al'*Bh)/2048.
// Block = 1 row (96 px) x 128 co, 4 waves; wave = 3 m-tiles x 4 n-tiles.
// B direct from global (fragment-ordered wt2), prefetched one tap ahead;
// x register-prefetched one chunk ahead. 2 blocks/CU.
// Grid 1536 = exactly 3 residency rounds at 2 blocks/CU.
//
// CONV STRUCTURE LEDGER (unified 512 regs/lane/SIMD, gfx950) — do not retry:
//   R5 4-wave 256thr: 128 VGPR + 96 AGPR = 224/wave, 2 waves/SIMD -> 240us
//   R2 +32 VGPR prefetch: spill (FETCH +315 MB) -> 417us
//   R6 8-wave (512,4): launch_bounds 2nd arg = MIN BLOCKS/CU (CUDA
//      semantics) -> VGPR cap 64 -> spill -> 417us (but 112/wave DID
//      fit 4 waves/SIMD)
//   R7 8-wave (512,2): 80+48=128/wave -> only 1 block/CU (threshold<128)
//   R8 8-wave no-prefetch: 84+48=132/wave -> 1 block/CU, 286us.
//   8-wave needs <=~76 VGPR; address-math floor is ~84. ABANDONED.
//
// Y-BAND XCD SWIZZLE: with round-robin bid%8 -> XCD dispatch, XCD k gets
// rows [12k,12k+12) for ALL (cb,ks).
// Epilogue LDS tile padded 96x132 f32 (breaks 4-way store bank conflict).
// ---------------------------------------------------------------------------
__global__ __launch_bounds__(256, 2) void k_conv(
    const _Float16* __restrict__ xth, const _Float16* __restrict__ xtl,
    const _Float16* __restrict__ wt2, float* __restrict__ hp) {
    __shared__ __align__(16) char smem[50688];   // xs 47040 B; epilogue 96x132 f32
    _Float16* xs = (_Float16*)smem;

    const int tid = threadIdx.x;
    const int bid = blockIdx.x;
    const int xcd = bid & 7;
    const int i8  = bid >> 3;          // 0..191
    const int y   = xcd * 12 + (i8 % 12);
    const int cbks = i8 / 12;          // 0..15
    const int cb  = cbks & 3;          // co block of 128
    const int ks  = cbks >> 2;         // K-split quarter (0..3)
    const int l  = tid & 63;
    const int wv = tid >> 6;          // 0..3
    const int mg = wv & 1;            // m-group
    const int ng = wv >> 1;           // n-group
    const int lm = l & 15;
    const int lk = l >> 4;            // 0..3

    f32x4 acc_h[3][4];
    f32x4 acc_x[3][4];
#pragma unroll
    for (int m2 = 0; m2 < 3; ++m2)
#pragma unroll
        for (int nt = 0; nt < 4; ++nt) {
            acc_h[m2][nt] = (f32x4){0.f, 0.f, 0.f, 0.f};
            acc_x[m2][nt] = (f32x4){0.f, 0.f, 0.f, 0.f};
        }

    // zero px pad columns (pxp = 0 and 97), both planes, 3 rows
    for (int i = tid; i < 480; i += 256) {
        int pl = i / 240, j = i - pl * 240;
        int r = j / 80, j2 = j - r * 80;
        int side = j2 / 40, c = j2 - side * 40;
        xs[pl * XS_PLANE + (r * 98 + side * 97) * CIP + c] = (_Float16)0.f;
    }

    auto ldx = [&](float4* xr, int cc_) {
#pragma unroll
        for (int k = 0; k < 9; ++k) {
            int item = k * 256 + tid;
            int pl = (item >= 1152) ? 1 : 0;
            int j = item - pl * 1152;
            int r = j / 384, j2 = j - r * 384;
            int px = j2 >> 2, q = j2 & 3;
            int yy = y + r - 1;
            float4 v = {0.f, 0.f, 0.f, 0.f};
            if (yy >= 0 && yy < H)
                v = *(const float4*)((pl ? xtl : xth) + (size_t)(yy * 96 + px) * 1024 + cc_ * 32 + q * 8);
            xr[k] = v;
        }
    };
    auto stx = [&](const float4* xr) {
#pragma unroll
        for (int k = 0; k < 9; ++k) {
            int item = k * 256 + tid;
            int pl = (item >= 1152) ? 1 : 0;
            int j = item - pl * 1152;
            int r = j / 384, j2 = j - r * 384;
            int px = j2 >> 2, q = j2 & 3;
            *(float4*)(xs + pl * XS_PLANE + (r * 98 + px + 1) * CIP + q * 8) = xr[k];
        }
    };
    auto ldb = [&](half8_t* bh, half8_t* bl, int cc_, int tap_) {
        const _Float16* base = wt2 + ((size_t)((tap_ * 4 + cb) * 32 + cc_) * 16) * 512 + (size_t)l * 8;
#pragma unroll
        for (int nt = 0; nt < 4; ++nt) {
            bh[nt] = *(const half8_t*)(base + (size_t)(ng * 4 + nt) * 512);
            bl[nt] = *(const half8_t*)(base + (size_t)(8 + ng * 4 + nt) * 512);
        }
    };

    const int cc0 = ks * 8;
    const int ccE = cc0 + 8;
    float4 xr[9];
    ldx(xr, cc0);
    half8_t bnh[4], bnl[4];
    ldb(bnh, bnl, cc0, 0);

    for (int cc = cc0; cc < ccE; ++cc) {
        __syncthreads();           // previous chunk's xs reads complete
        stx(xr);
        __syncthreads();           // xs visible
        const int ccn = (cc + 1 < ccE) ? cc + 1 : cc;
        ldx(xr, ccn);              // prefetch next chunk's x (in flight during taps)

#pragma unroll
        for (int tap = 0; tap < 9; ++tap) {
            half8_t bh[4], bl[4];
#pragma unroll
            for (int nt = 0; nt < 4; ++nt) { bh[nt] = bnh[nt]; bl[nt] = bnl[nt]; }
            const int ntap = (tap == 8) ? 0 : tap + 1;
            const int ncc  = (tap == 8) ? ccn : cc;
            ldb(bnh, bnl, ncc, ntap);   // prefetch next tap's B

            const int ky = tap / 3, kx = tap - 3 * (tap / 3);
            half8_t ah[3], al[3];
#pragma unroll
            for (int m2 = 0; m2 < 3; ++m2) {
                const int pxp = (mg * 3 + m2) * 16 + lm + kx;
                ah[m2] = *(const half8_t*)(xs + (ky * 98 + pxp) * CIP + lk * 8);
                al[m2] = *(const half8_t*)(xs + XS_PLANE + (ky * 98 + pxp) * CIP + lk * 8);
            }
#pragma unroll
            for (int m2 = 0; m2 < 3; ++m2)
#pragma unroll
                for (int nt = 0; nt < 4; ++nt)
                    acc_h[m2][nt] = __builtin_amdgcn_mfma_f32_16x16x32_f16(ah[m2], bh[nt], acc_h[m2][nt], 0, 0, 0);
#pragma unroll
            for (int m2 = 0; m2 < 3; ++m2)
#pragma unroll
                for (int nt = 0; nt < 4; ++nt)
                    acc_x[m2][nt] = __builtin_amdgcn_mfma_f32_16x16x32_f16(ah[m2], bl[nt], acc_x[m2][nt], 0, 0, 0);
#pragma unroll
            for (int m2 = 0; m2 < 3; ++m2)
#pragma unroll
                for (int nt = 0; nt < 4; ++nt)
                    acc_x[m2][nt] = __builtin_amdgcn_mfma_f32_16x16x32_f16(al[m2], bh[nt], acc_x[m2][nt], 0, 0, 0);
        }
    }

    // ---- epilogue: combine planes, bounce through LDS, coalesced store ----
    __syncthreads();
    float* cs = (float*)smem;
#pragma unroll
    for (int m2 = 0; m2 < 3; ++m2)
#pragma unroll
        for (int nt = 0; nt < 4; ++nt) {
            int co = (ng * 4 + nt) * 16 + lm;
#pragma unroll
            for (int r = 0; r < 4; ++r) {
                int px = (mg * 3 + m2) * 16 + lk * 4 + r;
                cs[px * 132 + co] = acc_h[m2][nt][r] + acc_x[m2][nt][r] * (1.f / 2048.f);
            }
        }
    __syncthreads();
    float4* dst = (float4*)(hp + ((size_t)(ks * 4 + cb) * NPIX + y * 96) * 128);
    for (int i = tid; i < 3072; i += 256) {
        int px = i >> 5, c4 = i & 31;
        dst[i] = *(const float4*)(cs + px * 132 + c4 * 4);
    }
}

// ---------------------------------------------------------------------------
// fused post+decode. R11.
// Phase 1 (post): h = relu(hp0..hp3 + b_rpn) for 18 px staged in LDS;
// 1x1 convs (54 ch) -> outs[18][56] in LDS (accum buffer ELIMINATED).
// 512 blocks x 18 px = exactly 2 blocks/CU, load-balanced (old 384-block
// version left half the CUs with 1 block while the other half ran 2).
// Phase 2 (decode): the block's 162 anchors decoded from LDS outs;
// props/boxes stored as coalesced float4 (old k_decode: scalar stores at
// 16B lane stride = 4x line over-fetch + scattered accum re-reads).
// ---------------------------------------------------------------------------
__device__ __forceinline__ unsigned int key_of(float d) {
    unsigned int u = __float_as_uint(d);
    unsigned int k = (u & 0x80000000u) ? ~u : (u | 0x80000000u);  // asc in d
    return ~k;                                                     // asc key = desc d
}

__global__ __launch_bounds__(256, 2) void k_postdec(const float* __restrict__ hp,
                                                    const float* __restrict__ br,
                                                    const float* __restrict__ wcl,
                                                    const float* __restrict__ wrg,
                                                    const float* __restrict__ bcl,
                                                    const float* __restrict__ brg,
                                                    const float* __restrict__ anchors,
                                                    float* __restrict__ props,
                                                    float* __restrict__ boxes,
                                                    float* __restrict__ cls2,
                                                    float* __restrict__ dval,
                                                    unsigned int* __restrict__ hist) {
    __shared__ float hsm[18 * 520];    // 37.4 KB
    __shared__ float wcs[54 * 130];    // 28.1 KB
    __shared__ float outs[18 * 56];    //  4.0 KB  (total 69.5 KB, 2/CU = 139 < 160)
    const int tid = threadIdx.x;
    const int gp0 = blockIdx.x * 18;

    for (int i = tid; i < 18 * 512; i += 256) {
        int px = i >> 9, ci = i & 511;
        int cbk = ci >> 7, co = ci & 127;
        size_t off = ((size_t)cbk * NPIX + gp0 + px) * 128 + co;
        float v = hp[off] + hp[off + HP_SPLIT] + hp[off + 2 * (size_t)HP_SPLIT] +
                  hp[off + 3 * (size_t)HP_SPLIT] + br[ci];
        hsm[px * 520 + ci] = fmaxf(v, 0.f);
    }

    const int px  = tid >> 3;
    const int chb = tid & 7;
    float part[7];
#pragma unroll
    for (int k = 0; k < 7; ++k) part[k] = 0.f;

    for (int chunk = 0; chunk < 4; ++chunk) {
        __syncthreads();
        for (int i = tid; i < 54 * 128; i += 256) {
            int ch = i >> 7, j = i & 127;
            wcs[ch * 130 + j] = (ch < 18) ? wcl[ch * 512 + chunk * 128 + j]
                                          : wrg[(ch - 18) * 512 + chunk * 128 + j];
        }
        __syncthreads();
        if (px < 18) {
            const float4* hv = (const float4*)(hsm + px * 520 + chunk * 128);
#pragma unroll 4
            for (int q = 0; q < 32; ++q) {
                float4 hq = hv[q];
#pragma unroll
                for (int k = 0; k < 7; ++k) {
                    int ch = chb * 7 + k;
                    if (ch < 54) {
                        float4 wq = *(const float4*)(wcs + ch * 130 + q * 4);
                        part[k] += hq.x * wq.x + hq.y * wq.y + hq.z * wq.z + hq.w * wq.w;
                    }
                }
            }
        }
    }
    if (px < 18) {
#pragma unroll
        for (int k = 0; k < 7; ++k) {
            int ch = chb * 7 + k;
            if (ch < 54) {
                float b = (ch < 18) ? bcl[ch] : brg[ch - 18];
                outs[px * 56 + ch] = part[k] + b;
            }
        }
    }
    __syncthreads();

    // ---- decode the block's 18*9 = 162 anchors from LDS ----
    if (tid < 162) {
        const int px2 = tid / 9, a = tid - px2 * 9;
        const float* ac = outs + px2 * 56;
        const int idx = (gp0 + px2) * 9 + a;
        float c0 = ac[2 * a], c1 = ac[2 * a + 1];
        float r0 = ac[18 + 4 * a + 0], r1 = ac[18 + 4 * a + 1];
        float r2 = ac[18 + 4 * a + 2], r3 = ac[18 + 4 * a + 3];
        float4 A = ((const float4*)anchors)[idx];
        float aw = A.z - A.x + 1.f, ah = A.w - A.y + 1.f;
        float ax = A.x + 0.5f * (aw - 1.f), ay = A.y + 0.5f * (ah - 1.f);
        float pcx = ax + aw * r0, pcy = ay + ah * r1;
        float pw = aw * expf(r2), ph = ah * expf(r3);
        float p0 = pcx - 0.5f * (pw - 1.f), p1 = pcy - 0.5f * (ph - 1.f);
        float p2 = pcx + 0.5f * (pw - 1.f), p3 = pcy + 0.5f * (ph - 1.f);
        float4 pr; pr.x = p0; pr.y = p1; pr.z = p2; pr.w = p3;
        ((float4*)props)[idx] = pr;
        float4 bx;
        bx.x = fminf(fmaxf(p0, 0.f), (float)(1536 - 1));
        bx.y = fminf(fmaxf(p1, 0.f), (float)(1536 - 1));
        bx.z = fminf(fmaxf(p2, 0.f), (float)(1536 - 1));
        bx.w = fminf(fmaxf(p3, 0.f), (float)(1536 - 1));
        ((float4*)boxes)[idx] = bx;
        float2 cl; cl.x = c0; cl.y = c1;
        ((float2*)cls2)[idx] = cl;
        float d = c1 - c0;
        dval[idx] = d;
        atomicAdd(&hist[key_of(d) >> 16], 1u);
    }
}

// ---------------------------------------------------------------------------
// threshold: find histogram bin T containing rank-6000.
// R4: wave-reduce before LDS atomic (old: 64-way same-address LDS-atomic
// serialization, ~25us on one CU). shfl tree + 1 atomic per wave-iteration.
// ---------------------------------------------------------------------------
__global__ __launch_bounds__(1024) void k_thresh(const unsigned int* __restrict__ hist,
                                                 unsigned int* __restrict__ ctrl) {
    __shared__ unsigned int s[256];
    __shared__ unsigned int ss[256];
    __shared__ unsigned int chunkIdx, baseCount;
    const int tid = threadIdx.x;
    if (tid < 256) s[tid] = 0u;
    __syncthreads();
    for (int i = tid; i < 65536; i += 1024) {
        unsigned int v = hist[i];
#pragma unroll
        for (int d = 32; d > 0; d >>= 1) v += __shfl_down(v, d);
        if ((tid & 63) == 0) atomicAdd(&s[i >> 8], v);
    }
    __syncthreads();
    if (tid == 0) {
        unsigned int cum = 0; int c = 0;
        for (; c < 256; ++c) { if (cum + s[c] >= TOPN) break; cum += s[c]; }
        chunkIdx = (unsigned int)c; baseCount = cum;
    }
    __syncthreads();
    if (tid < 256) ss[tid] = hist[chunkIdx * 256 + tid];
    __syncthreads();
    if (tid == 0) {
        unsigned int cum = baseCount; int b = 0;
        for (; b < 256; ++b) { cum += ss[b]; if (cum >= TOPN) break; }
        ctrl[1] = chunkIdx * 256 + (unsigned int)b;  // T
        ctrl[2] = cum;
    }
}

// ---------------------------------------------------------------------------
// compact candidates (bin <= T): per-block LDS aggregation, 1 global atomic.
// ---------------------------------------------------------------------------
__global__ __launch_bounds__(256) void k_compact(const float* __restrict__ dval,
                                                 unsigned int* __restrict__ ctrl,
                                                 unsigned long long* __restrict__ cand) {
    __shared__ unsigned int cnt, base;
    const int tid = threadIdx.x;
    const int idx = blockIdx.x * 256 + tid;
    if (tid == 0) cnt = 0u;
    __syncthreads();
    unsigned int k2 = 0; bool pass = false; unsigned int pos = 0;
    if (idx < NA) {
        k2 = key_of(dval[idx]);
        pass = (k2 >> 16) <= ctrl[1];
        if (pass) pos = atomicAdd(&cnt, 1u);
    }
    __syncthreads();
    if (tid == 0) base = atomicAdd(&ctrl[0], cnt);
    __syncthreads();
    if (pass) {
        unsigned int p = base + pos;
        if (p < CAND_CAP) cand[p] = ((unsigned long long)k2 << 32) | (unsigned int)idx;
    }
}

// ---------------------------------------------------------------------------
// rank-by-count, j-range split 8 ways: block (ci,jq) ranks candidates
// ci*256..+256 against key slice jq*1024..+1024, WRITES partial rank to
// rankp[jq*CAND_CAP + i] (no atomics, no init).
// ---------------------------------------------------------------------------
__global__ __launch_bounds__(256) void k_rankp(const unsigned long long* __restrict__ cand,
                                               const unsigned int* __restrict__ ctrl,
                                               unsigned int* __restrict__ rankp) {
    __shared__ unsigned long long sc[RCHUNK];   // 8 KB
    const int tid = threadIdx.x;
    const int ci = blockIdx.x >> 3;            // candidate chunk 0..31
    const int jq = blockIdx.x & 7;             // j-slice 0..7
    unsigned int n = ctrl[0]; if (n > CAND_CAP) n = CAND_CAP;
    const int jb = jq * RCHUNK;
    for (int i = tid; i < RCHUNK; i += 256) {
        int j = jb + i;
        sc[i] = (j < (int)n) ? cand[j] : 0xFFFFFFFFFFFFFFFFull;  // pads never < mine
    }
    __syncthreads();
    const int i = ci * 256 + tid;
    // keep ALL lanes active through the shfl loop (inactive lanes would
    // poison __shfl reads for their wave-mates)
    const unsigned long long mine = (i < (int)n) ? cand[i] : 0xFFFFFFFFFFFFFFFFull;
    const int l = tid & 63;
    int nq = (int)n - jb; if (nq < 0) nq = 0; if (nq > RCHUNK) nq = RCHUNK;
    const int nr = (nq + 63) & ~63;
    int rank = 0;
    for (int j0 = 0; j0 < nr; j0 += 64) {
        unsigned long long kj = sc[j0 + l];
#pragma unroll
        for (int b = 0; b < 64; ++b) {
            unsigned long long kb = __shfl(kj, b);
            rank += (kb < mine) ? 1 : 0;
        }
    }
    if (i < (int)n) rankp[jq * CAND_CAP + i] = (unsigned int)rank;
}

// ---------------------------------------------------------------------------
// sum the 8 partial ranks, scatter boxes/probs at final rank.
// ---------------------------------------------------------------------------
__global__ __launch_bounds__(256) void k_ranks(const unsigned long long* __restrict__ cand,
                                               const unsigned int* __restrict__ ctrl,
                                               const unsigned int* __restrict__ rankp,
                                               const float* __restrict__ boxes,
                                               const float* __restrict__ dval,
                                               float* __restrict__ topBoxes,
                                               float* __restrict__ topProbs) {
    const int i = blockIdx.x * 256 + threadIdx.x;
    unsigned int n = ctrl[0]; if (n > CAND_CAP) n = CAND_CAP;
    if (i >= (int)n) return;
    unsigned int rank = 0;
#pragma unroll
    for (int q = 0; q < RQ; ++q) rank += rankp[q * CAND_CAP + i];
    if (rank < TOPN) {
        unsigned long long mine = cand[i];
        unsigned int idx = (unsigned int)mine;
        ((float4*)topBoxes)[rank] = ((const float4*)boxes)[idx];
        topProbs[rank] = 1.f / (1.f + expf(-dval[idx]));
    }
}

// ---------------------------------------------------------------------------
// NMS suppression bitmask, triangular grid.
// R9: TRANSPOSED mask layout maskT[ci][c2][b] (ci=i>>6, b=i&63),
// 94*94*64 u64 = 4.523 MB. k_scan's c2-sweep reads one CONTIGUOUS
// (NW-c)*512 B stream per iteration instead of 8B words 752 B apart.
// maskT[93][*][48..63] never written; k_scan consumes those lanes only
// under w-bits that are 0 by construction (kw[93] init masks b>=48).
// R4: c-block's 64 boxes staged in LDS; whole-block diagonal early-out.
// ---------------------------------------------------------------------------
__global__ __launch_bounds__(256) void k_mask(const float* __restrict__ topBoxes,
                                              unsigned long long* __restrict__ mask) {
    const int c = blockIdx.y;
    if (c < blockIdx.x * 4) return;            // whole block below diagonal
    __shared__ float4 bsh[64];
    const int tid = threadIdx.x;
    const int i = blockIdx.x * 256 + tid;
    if (tid < 64) {
        int j = c * 64 + tid;
        float4 bv = {0.f, 0.f, 0.f, 0.f};
        if (j < TOPN) bv = ((const float4*)topBoxes)[j];
        bsh[tid] = bv;
    }
    __syncthreads();
    if (i >= TOPN || c < (i >> 6)) return;
    float4 bi = ((const float4*)topBoxes)[i];
    float ai = (bi.z - bi.x + 1.f) * (bi.w - bi.y + 1.f);
    unsigned long long m = 0;
    int j0 = c * 64;
    for (int b = 0; b < 64; ++b) {
        int j = j0 + b;
        if (j >= TOPN || j <= i) continue;
        float4 bj = bsh[b];
        float aj = (bj.z - bj.x + 1.f) * (bj.w - bj.y + 1.f);
        float iw = fmaxf(fminf(bi.z, bj.z) - fmaxf(bi.x, bj.x) + 1.f, 0.f);
        float ih = fmaxf(fminf(bi.w, bj.w) - fmaxf(bi.y, bj.y) + 1.f, 0.f);
        float inter = iw * ih;
        float iou = inter / (ai + aj - inter);
        if (iou > 0.7f) m |= (1ull << b);
    }
    // transposed store: maskT[i>>6][c][i&63]
    mask[((size_t)(i >> 6) * NW + c) * 64 + (i & 63)] = m;
}

// ---------------------------------------------------------------------------
// greedy scan, single wave, batched unconditional loads, early exit at 300.
// [R3-proven control flow; R9 remapped mask indices to transposed layout.]
// ---------------------------------------------------------------------------
__global__ __launch_bounds__(64) void k_scan(const unsigned long long* __restrict__ mask,
                                             const float* __restrict__ topBoxes,
                                             const float* __restrict__ topProbs,
                                             float* __restrict__ out2, float* __restrict__ out3) {
    __shared__ unsigned long long kw[NW];
    int l = threadIdx.x;
    for (int i = l; i < NW; i += 64)
        kw[i] = (i == NW - 1) ? 0x0000FFFFFFFFFFFFull : ~0ull;  // 6000 = 93*64+48
    __syncthreads();
    int kept = 0;
    for (int c = 0; c < NW && kept < POSN; ++c) {
        unsigned long long w = kw[c];
        unsigned long long m = mask[((size_t)c * NW + c) * 64 + l];   // maskT[c][c][l]
        for (int b = 0; b < 64; ++b) {
            if ((w >> b) & 1ull) {
                unsigned long long mb = __shfl(m, b);
                w &= ~mb;
            }
        }
        if ((w >> l) & 1ull) {
            int r = kept + __popcll(w & ((1ull << l) - 1ull));
            if (r < POSN) {
                int j = c * 64 + l;
                out2[r * 4 + 0] = topBoxes[j * 4 + 0];
                out2[r * 4 + 1] = topBoxes[j * 4 + 1];
                out2[r * 4 + 2] = topBoxes[j * 4 + 2];
                out2[r * 4 + 3] = topBoxes[j * 4 + 3];
                out3[r] = topProbs[j];
            }
        }
        kept += __popcll(w);
        if (kept >= POSN) break;
        for (int c2 = c + 1 + l; c2 < NW; c2 += 64) {
            const unsigned long long* mrow = mask + ((size_t)c * NW + c2) * 64;  // maskT[c][c2][*]
            unsigned long long sup = 0;
#pragma unroll
            for (int b0 = 0; b0 < 64; b0 += 16) {
                unsigned long long t[16];
#pragma unroll
                for (int j = 0; j < 16; ++j)
                    t[j] = mrow[b0 + j];
#pragma unroll
                for (int j = 0; j < 16; ++j)
                    sup |= ((w >> (b0 + j)) & 1ull) ? t[j] : 0ull;
            }
            kw[c2] &= ~sup;
        }
        __syncthreads();
    }
    for (int r = kept + l; r < POSN; r += 64) {
        out2[r * 4 + 0] = 0.f; out2[r * 4 + 1] = 0.f;
        out2[r * 4 + 2] = 0.f; out2[r * 4 + 3] = 0.f;
        out3[r] = 0.f;
    }
}

// ---------------------------------------------------------------------------
// gather proposals/cls at valid_idx
// ---------------------------------------------------------------------------
__global__ void k_gather(const int* __restrict__ vidx, const float* __restrict__ props,
                         const float* __restrict__ cls2, float* __restrict__ out0,
                         float* __restrict__ out1, int nv) {
    int i = blockIdx.x * 256 + threadIdx.x;
    if (i >= nv) return;
    int v = vidx[i];
    ((float4*)out0)[i] = ((const float4*)props)[v];
    ((float2*)out1)[i] = ((const float2*)cls2)[v];
}

// ---------------------------------------------------------------------------
extern "C" void kernel_launch(void* const* d_in, const int* in_sizes, int n_in,
                              void* d_out, int out_size, void* d_ws, size_t ws_size,
                              hipStream_t stream) {
    const float* x       = (const float*)d_in[0];
    const float* w_rpn   = (const float*)d_in[1];
    const float* b_rpn   = (const float*)d_in[2];
    const float* w_cls   = (const float*)d_in[3];
    const float* b_cls   = (const float*)d_in[4];
    const float* w_reg   = (const float*)d_in[5];
    const float* b_reg   = (const float*)d_in[6];
    const float* anchors = (const float*)d_in[7];
    const int*   vidx    = (const int*)d_in[8];
    const int nv = in_sizes[8];

    char* ws = (char*)d_ws;
    float* props            = (float*)(ws + 1990656);
    float* boxes            = (float*)(ws + 3317760);
    float* cls2             = (float*)(ws + 4644864);
    float* dval             = (float*)(ws + 5308416);
    unsigned int* hist      = (unsigned int*)(ws + 5640192);
    unsigned int* ctrl      = (unsigned int*)(ws + 5902336);
    unsigned long long* cand = (unsigned long long*)(ws + 5902400);
    float* topBoxes         = (float*)(ws + 5967936);
    float* topProbs         = (float*)(ws + 6063936);
    unsigned long long* mask = (unsigned long long*)(ws + 6087936);  // transposed maskT: 94*94*512 = 4.523 MB (ends 10610944)
    _Float16* xt_h          = (_Float16*)(ws + 10599936);  // 18.87 MB (first 11 KB overlapped by maskT tail — xt_h dead before k_mask)
    _Float16* xt_l          = (_Float16*)(ws + 29474304);  // 18.87 MB
    _Float16* wt2           = (_Float16*)(ws + 48348672);  // 18.87 MB fragment-ordered
    float* hp               = (float*)(ws + 67223040);     // 75.5 MB (4 K-splits; ends ~143 MB)
    // partial ranks (8 x 8192 u32 = 256 KB) in xt_h's dead region, placed
    // 16 KB past its start so maskT's 11 KB tail (ends at 10610944) can
    // never alias rankp even though both outlive k_rankp/k_ranks.
    unsigned int* rankp     = (unsigned int*)(ws + 10616320);

    float* out0 = (float*)d_out;
    float* out1 = out0 + (size_t)nv * 4;
    float* out2 = out1 + (size_t)nv * 2;
    float* out3 = out2 + (size_t)POSN * 4;

    k_xtr<<<dim3(144, 16), 256, 0, stream>>>(x, xt_h, xt_l, hist, ctrl);
    k_wtr<<<dim3(4, 32, 4), 256, 0, stream>>>(w_rpn, wt2);
    k_conv<<<1536, 256, 0, stream>>>(xt_h, xt_l, wt2, hp);
    k_postdec<<<512, 256, 0, stream>>>(hp, b_rpn, w_cls, w_reg, b_cls, b_reg,
                                       anchors, props, boxes, cls2, dval, hist);
    k_thresh<<<1, 1024, 0, stream>>>(hist, ctrl);
    k_compact<<<(NA + 255) / 256, 256, 0, stream>>>(dval, ctrl, cand);
    k_rankp<<<32 * RQ, 256, 0, stream>>>(cand, ctrl, rankp);
    k_ranks<<<32, 256, 0, stream>>>(cand, ctrl, rankp, boxes, dval, topBoxes, topProbs);
    k_mask<<<dim3(24, NW), 256, 0, stream>>>(topBoxes, mask);
    k_scan<<<1, 64, 0, stream>>>(mask, topBoxes, topProbs, out2, out3);
    k_gather<<<(nv + 255) / 256, 256, 0, stream>>>(vidx, props, cls2, out0, out1, nv);
}